// Round 1
// baseline (172.646 us; speedup 1.0000x reference)
//
#include <hip/hip_runtime.h>
#include <hip/hip_bf16.h>
#include <stdint.h>

#define NH 16
#define HID 1024
#define HD 64
#define NB 4
#define SS 1024
#define MTOT (NB*SS)   // 4096

typedef __attribute__((ext_vector_type(8))) short bf16x8;
typedef __attribute__((ext_vector_type(4))) float f32x4;

__device__ __forceinline__ unsigned short f2bf(float f) {
  union { float f; unsigned u; } v; v.f = f;
  unsigned u = v.u;
  return (unsigned short)((u + 0x7FFFu + ((u >> 16) & 1u)) >> 16);
}

__device__ __forceinline__ void async16(void* lds, const void* g) {
  __builtin_amdgcn_global_load_lds(
      (const __attribute__((address_space(1))) unsigned*)g,
      (__attribute__((address_space(3))) unsigned*)lds, 16, 0, 0);
}

// ---------------- fp32 -> bf16 conversion of X and W ----------------
__global__ void cvt_all(const float4* __restrict__ X,
                        const float4* __restrict__ Wq,
                        const float4* __restrict__ Wk,
                        const float4* __restrict__ Wv,
                        ushort4* __restrict__ Xb,
                        ushort4* __restrict__ Wb) {
  int i = blockIdx.x * 256 + threadIdx.x;   // 1835008 total
  const float4* src; ushort4* dst; int idx;
  if (i < (MTOT * HID / 4)) {               // 1048576 float4 of X
    src = X; dst = Xb; idx = i;
  } else {
    int j = i - (MTOT * HID / 4);           // 786432 float4 of W
    int sel = j >> 18;                      // 262144 float4 per W
    idx = j & 262143;
    src = (sel == 0) ? Wq : (sel == 1) ? Wk : Wv;
    dst = Wb + (size_t)sel * 262144;
  }
  float4 v = src[idx];
  ushort4 o;
  o.x = f2bf(v.x); o.y = f2bf(v.y); o.z = f2bf(v.z); o.w = f2bf(v.w);
  dst[idx] = o;
}

// ---------------- fused QKV projection GEMM ----------------
// C[m][n] = sum_k Xb[m][k] * Wb[n][k] + bias[n];  M=4096, N=3072, K=1024
// Q rows pre-scaled by 0.125 (HEAD_DIM^-0.5), V written transposed.
__global__ __launch_bounds__(256) void qkv_gemm(
    const ushort* __restrict__ Xb,    // [4096][1024] bf16
    const ushort* __restrict__ Wb,    // [3072][1024] bf16 (Wq|Wk|Wv)
    const float* __restrict__ bq,
    const float* __restrict__ bk,
    const float* __restrict__ bv,
    ushort* __restrict__ Q,           // [B*H][S][64]
    ushort* __restrict__ K,           // [B*H][S][64]
    ushort* __restrict__ Vt)          // [B*H][64][S]
{
  __shared__ ushort Al[128 * 64];     // 16 KB
  __shared__ ushort Bl[128 * 64];     // 16 KB

  int bid = blockIdx.x;               // 768 blocks
  int swz = (bid & 7) * 96 + (bid >> 3);  // XCD-aware swizzle (768 % 8 == 0)
  const int nbn = 3072 / 128;         // 24
  int bm = swz / nbn, bn = swz % nbn;
  int m0 = bm * 128, n0 = bn * 128;

  int tid = threadIdx.x;
  int wave = tid >> 6, lane = tid & 63;
  int g = lane >> 4, c = lane & 15;
  int wr = wave >> 1, wc = wave & 1;  // 2x2 waves, each 64x64 output

  const ushort* Asrc = Xb + (size_t)(m0 + (tid >> 3)) * 1024 + (tid & 7) * 8;
  const ushort* Bsrc = Wb + (size_t)(n0 + (tid >> 3)) * 1024 + (tid & 7) * 8;

  f32x4 acc[4][4] = {};

  for (int ks = 0; ks < 16; ++ks) {
    int k0 = ks * 64;
    __syncthreads();                 // previous compute done, LDS reusable
    #pragma unroll
    for (int i = 0; i < 4; ++i) {
      async16((char*)Al + i * 4096 + wave * 1024, Asrc + (size_t)i * 32 * 1024 + k0);
      async16((char*)Bl + i * 4096 + wave * 1024, Bsrc + (size_t)i * 32 * 1024 + k0);
    }
    __syncthreads();                 // vmcnt(0) drain: tiles ready
    #pragma unroll
    for (int kk = 0; kk < 2; ++kk) {
      bf16x8 a[4], b[4];
      #pragma unroll
      for (int m = 0; m < 4; ++m)
        a[m] = *(const bf16x8*)((const char*)Al + (wr * 64 + m * 16 + c) * 128 + kk * 64 + g * 16);
      #pragma unroll
      for (int n = 0; n < 4; ++n)
        b[n] = *(const bf16x8*)((const char*)Bl + (wc * 64 + n * 16 + c) * 128 + kk * 64 + g * 16);
      #pragma unroll
      for (int m = 0; m < 4; ++m)
        #pragma unroll
        for (int n = 0; n < 4; ++n)
          acc[m][n] = __builtin_amdgcn_mfma_f32_16x16x32_bf16(a[m], b[n], acc[m][n], 0, 0, 0);
    }
  }

  int sel = n0 >> 10;                 // uniform per block (128 | 1024)
  const float* bp = (sel == 0) ? bq : (sel == 1) ? bk : bv;
  float scl = (sel == 0) ? 0.125f : 1.0f;

  #pragma unroll
  for (int n = 0; n < 4; ++n) {
    int nn = (n0 & 1023) + wc * 64 + n * 16 + c;   // 0..1023 within Q/K/V
    float bias = bp[nn];
    int h = nn >> 6, d = nn & 63;
    #pragma unroll
    for (int m = 0; m < 4; ++m) {
      int rowg = m0 + wr * 64 + m * 16 + g * 4;
      int bb = rowg >> 10;
      int s = rowg & 1023;
      #pragma unroll
      for (int r = 0; r < 4; ++r) {
        float val = (acc[m][n][r] + bias) * scl;
        unsigned short ob = f2bf(val);
        if (sel == 0)
          Q[(size_t)((bb * 16 + h) * 1024 + s + r) * 64 + d] = ob;
        else if (sel == 1)
          K[(size_t)((bb * 16 + h) * 1024 + s + r) * 64 + d] = ob;
        else
          Vt[(size_t)((bb * 16 + h) * 64 + d) * 1024 + s + r] = ob;
      }
    }
  }
}

// ---------------- flash attention ----------------
// grid = B*H*(S/64) = 1024 blocks; 4 waves/block, each wave 16 q-rows.
__global__ __launch_bounds__(256) void attn(
    const ushort* __restrict__ Q,    // [B*H][S][64], pre-scaled by 0.125
    const ushort* __restrict__ K,    // [B*H][S][64]
    const ushort* __restrict__ Vt,   // [B*H][64][S]
    const float* __restrict__ mask,  // [B][S]
    float* __restrict__ out)         // [B][S][1024]
{
  __shared__ float mask_s[SS];               // 4 KB
  __shared__ ushort p_lds[4][16 * 32];       // per-wave P tile, 4 KB

  int blk = blockIdx.x;
  int bh = blk >> 4;
  int qt = blk & 15;
  int b = bh >> 4, h = bh & 15;
  int tid = threadIdx.x, wave = tid >> 6, lane = tid & 63;
  int g = lane >> 4, c = lane & 15;
  int q0 = qt * 64 + wave * 16;

  for (int i = tid; i < SS; i += 256) mask_s[i] = mask[b * SS + i];
  __syncthreads();

  const ushort* Qb = Q + (size_t)bh * SS * 64;
  const ushort* Kb = K + (size_t)bh * SS * 64;
  const ushort* Vb = Vt + (size_t)bh * 64 * SS;

  // Q fragments (A operand): row = c, k = g*8+j (+32 for second frag)
  bf16x8 qf0 = *(const bf16x8*)(Qb + (q0 + c) * 64 + g * 8);
  bf16x8 qf1 = *(const bf16x8*)(Qb + (q0 + c) * 64 + 32 + g * 8);

  f32x4 o[4] = {};                   // O[dim c4*16+c][row g*4+r]
  float mrow[4], lrow[4];
  #pragma unroll
  for (int r = 0; r < 4; ++r) { mrow[r] = -1e30f; lrow[r] = 0.f; }

  ushort* pl = p_lds[wave];

  for (int kv = 0; kv < SS; kv += 32) {
    // S tiles: s0 = keys kv..kv+15, s1 = keys kv+16..kv+31
    f32x4 s0 = {0.f, 0.f, 0.f, 0.f}, s1 = {0.f, 0.f, 0.f, 0.f};
    bf16x8 kf;
    kf = *(const bf16x8*)(Kb + (size_t)(kv + c) * 64 + g * 8);
    s0 = __builtin_amdgcn_mfma_f32_16x16x32_bf16(qf0, kf, s0, 0, 0, 0);
    kf = *(const bf16x8*)(Kb + (size_t)(kv + c) * 64 + 32 + g * 8);
    s0 = __builtin_amdgcn_mfma_f32_16x16x32_bf16(qf1, kf, s0, 0, 0, 0);
    kf = *(const bf16x8*)(Kb + (size_t)(kv + 16 + c) * 64 + g * 8);
    s1 = __builtin_amdgcn_mfma_f32_16x16x32_bf16(qf0, kf, s1, 0, 0, 0);
    kf = *(const bf16x8*)(Kb + (size_t)(kv + 16 + c) * 64 + 32 + g * 8);
    s1 = __builtin_amdgcn_mfma_f32_16x16x32_bf16(qf1, kf, s1, 0, 0, 0);

    float mk0 = mask_s[kv + c], mk1 = mask_s[kv + 16 + c];
    float mx[4];
    #pragma unroll
    for (int r = 0; r < 4; ++r) {
      s0[r] += mk0; s1[r] += mk1;
      mx[r] = fmaxf(s0[r], s1[r]);
    }
    #pragma unroll
    for (int d = 1; d < 16; d <<= 1) {
      #pragma unroll
      for (int r = 0; r < 4; ++r)
        mx[r] = fmaxf(mx[r], __shfl_xor(mx[r], d));
    }
    float p0[4], p1[4], rs[4], sc[4];
    #pragma unroll
    for (int r = 0; r < 4; ++r) {
      float mn = fmaxf(mrow[r], mx[r]);
      sc[r] = __expf(mrow[r] - mn);
      mrow[r] = mn;
      p0[r] = __expf(s0[r] - mn);
      p1[r] = __expf(s1[r] - mn);
      rs[r] = p0[r] + p1[r];
    }
    #pragma unroll
    for (int d = 1; d < 16; d <<= 1) {
      #pragma unroll
      for (int r = 0; r < 4; ++r)
        rs[r] += __shfl_xor(rs[r], d);
    }
    #pragma unroll
    for (int r = 0; r < 4; ++r) lrow[r] = lrow[r] * sc[r] + rs[r];
    #pragma unroll
    for (int c4 = 0; c4 < 4; ++c4)
      #pragma unroll
      for (int r = 0; r < 4; ++r)
        o[c4][r] *= sc[r];

    // P (S-layout) -> LDS -> A-fragment layout
    #pragma unroll
    for (int r = 0; r < 4; ++r) {
      pl[(g * 4 + r) * 32 + c]      = f2bf(p0[r]);
      pl[(g * 4 + r) * 32 + 16 + c] = f2bf(p1[r]);
    }
    __asm__ volatile("" ::: "memory");   // keep ds_write before ds_read (same-wave, HW in-order)
    bf16x8 pf = *(const bf16x8*)(pl + c * 32 + g * 8);
    #pragma unroll
    for (int c4 = 0; c4 < 4; ++c4) {
      bf16x8 vf = *(const bf16x8*)(Vb + (size_t)(c4 * 16 + c) * SS + kv + g * 8);
      o[c4] = __builtin_amdgcn_mfma_f32_16x16x32_bf16(pf, vf, o[c4], 0, 0, 0);
    }
  }

  #pragma unroll
  for (int c4 = 0; c4 < 4; ++c4) {
    #pragma unroll
    for (int r = 0; r < 4; ++r) {
      out[(size_t)(b * SS + q0 + g * 4 + r) * 1024 + h * 64 + c4 * 16 + c] =
          o[c4][r] / lrow[r];
    }
  }
}

extern "C" void kernel_launch(void* const* d_in, const int* in_sizes, int n_in,
                              void* d_out, int out_size, void* d_ws, size_t ws_size,
                              hipStream_t stream) {
  const float* hs   = (const float*)d_in[0];
  const float* mask = (const float*)d_in[1];
  const float* Wq   = (const float*)d_in[2];
  const float* bq   = (const float*)d_in[3];
  const float* Wk   = (const float*)d_in[4];
  const float* bk   = (const float*)d_in[5];
  const float* Wv   = (const float*)d_in[6];
  const float* bv   = (const float*)d_in[7];
  float* out = (float*)d_out;

  char* ws = (char*)d_ws;
  ushort* Xb = (ushort*)(ws);                    // 8 MB  [4096][1024]
  ushort* Wb = (ushort*)(ws + (8u  << 20));      // 6 MB  [3072][1024]
  ushort* Qp = (ushort*)(ws + (14u << 20));      // 8 MB  [64][1024][64]
  ushort* Kp = (ushort*)(ws + (22u << 20));      // 8 MB  [64][1024][64]
  ushort* Vt = (ushort*)(ws + (30u << 20));      // 8 MB  [64][64][1024]

  cvt_all<<<7168, 256, 0, stream>>>((const float4*)hs, (const float4*)Wq,
                                    (const float4*)Wk, (const float4*)Wv,
                                    (ushort4*)Xb, (ushort4*)Wb);
  qkv_gemm<<<768, 256, 0, stream>>>(Xb, Wb, bq, bk, bv, Qp, Kp, Vt);
  attn<<<1024, 256, 0, stream>>>(Qp, Kp, Vt, mask, out);
}

// Round 2
// 171.354 us; speedup vs baseline: 1.0075x; 1.0075x over previous
//
#include <hip/hip_runtime.h>
#include <hip/hip_bf16.h>
#include <stdint.h>

#define NH 16
#define HID 1024
#define HD 64
#define NB 4
#define SS 1024
#define MTOT (NB*SS)   // 4096

typedef __attribute__((ext_vector_type(8))) short bf16x8;
typedef __attribute__((ext_vector_type(4))) float f32x4;

__device__ __forceinline__ unsigned short f2bf(float f) {
  union { float f; unsigned u; } v; v.f = f;
  unsigned u = v.u;
  return (unsigned short)((u + 0x7FFFu + ((u >> 16) & 1u)) >> 16);
}

__device__ __forceinline__ unsigned pack2(float lo, float hi) {
  return (unsigned)f2bf(lo) | ((unsigned)f2bf(hi) << 16);
}

__device__ __forceinline__ void async16(void* lds, const void* g) {
  __builtin_amdgcn_global_load_lds(
      (const __attribute__((address_space(1))) unsigned*)g,
      (__attribute__((address_space(3))) unsigned*)lds, 16, 0, 0);
}

// ---------------- fp32 -> bf16 conversion of X and W ----------------
__global__ void cvt_all(const float4* __restrict__ X,
                        const float4* __restrict__ Wq,
                        const float4* __restrict__ Wk,
                        const float4* __restrict__ Wv,
                        ushort4* __restrict__ Xb,
                        ushort4* __restrict__ Wb) {
  int i = blockIdx.x * 256 + threadIdx.x;   // 1835008 total
  const float4* src; ushort4* dst; int idx;
  if (i < (MTOT * HID / 4)) {               // 1048576 float4 of X
    src = X; dst = Xb; idx = i;
  } else {
    int j = i - (MTOT * HID / 4);           // 786432 float4 of W
    int sel = j >> 18;                      // 262144 float4 per W
    idx = j & 262143;
    src = (sel == 0) ? Wq : (sel == 1) ? Wk : Wv;
    dst = Wb + (size_t)sel * 262144;
  }
  float4 v = src[idx];
  ushort4 o;
  o.x = f2bf(v.x); o.y = f2bf(v.y); o.z = f2bf(v.z); o.w = f2bf(v.w);
  dst[idx] = o;
}

// ---------------- fused QKV projection GEMM ----------------
__global__ __launch_bounds__(256) void qkv_gemm(
    const ushort* __restrict__ Xb,    // [4096][1024] bf16
    const ushort* __restrict__ Wb,    // [3072][1024] bf16 (Wq|Wk|Wv)
    const float* __restrict__ bq,
    const float* __restrict__ bk,
    const float* __restrict__ bv,
    ushort* __restrict__ Q,           // [B*H][S][64]
    ushort* __restrict__ K,           // [B*H][S][64]
    ushort* __restrict__ Vt)          // [B*H][64][S]
{
  __shared__ ushort Al[128 * 64];     // 16 KB
  __shared__ ushort Bl[128 * 64];     // 16 KB

  int bid = blockIdx.x;               // 768 blocks
  int swz = (bid & 7) * 96 + (bid >> 3);  // XCD-aware swizzle (768 % 8 == 0)
  const int nbn = 3072 / 128;         // 24
  int bm = swz / nbn, bn = swz % nbn;
  int m0 = bm * 128, n0 = bn * 128;

  int tid = threadIdx.x;
  int wave = tid >> 6, lane = tid & 63;
  int g = lane >> 4, c = lane & 15;
  int wr = wave >> 1, wc = wave & 1;  // 2x2 waves, each 64x64 output

  const ushort* Asrc = Xb + (size_t)(m0 + (tid >> 3)) * 1024 + (tid & 7) * 8;
  const ushort* Bsrc = Wb + (size_t)(n0 + (tid >> 3)) * 1024 + (tid & 7) * 8;

  f32x4 acc[4][4] = {};

  for (int ks = 0; ks < 16; ++ks) {
    int k0 = ks * 64;
    __syncthreads();
    #pragma unroll
    for (int i = 0; i < 4; ++i) {
      async16((char*)Al + i * 4096 + wave * 1024, Asrc + (size_t)i * 32 * 1024 + k0);
      async16((char*)Bl + i * 4096 + wave * 1024, Bsrc + (size_t)i * 32 * 1024 + k0);
    }
    __syncthreads();
    #pragma unroll
    for (int kk = 0; kk < 2; ++kk) {
      bf16x8 a[4], b[4];
      #pragma unroll
      for (int m = 0; m < 4; ++m)
        a[m] = *(const bf16x8*)((const char*)Al + (wr * 64 + m * 16 + c) * 128 + kk * 64 + g * 16);
      #pragma unroll
      for (int n = 0; n < 4; ++n)
        b[n] = *(const bf16x8*)((const char*)Bl + (wc * 64 + n * 16 + c) * 128 + kk * 64 + g * 16);
      #pragma unroll
      for (int m = 0; m < 4; ++m)
        #pragma unroll
        for (int n = 0; n < 4; ++n)
          acc[m][n] = __builtin_amdgcn_mfma_f32_16x16x32_bf16(a[m], b[n], acc[m][n], 0, 0, 0);
    }
  }

  int sel = n0 >> 10;
  const float* bp = (sel == 0) ? bq : (sel == 1) ? bk : bv;
  float scl = (sel == 0) ? 0.125f : 1.0f;

  #pragma unroll
  for (int n = 0; n < 4; ++n) {
    int nn = (n0 & 1023) + wc * 64 + n * 16 + c;
    float bias = bp[nn];
    int h = nn >> 6, d = nn & 63;
    #pragma unroll
    for (int m = 0; m < 4; ++m) {
      int rowg = m0 + wr * 64 + m * 16 + g * 4;
      int bb = rowg >> 10;
      int s = rowg & 1023;
      #pragma unroll
      for (int r = 0; r < 4; ++r) {
        float val = (acc[m][n][r] + bias) * scl;
        unsigned short ob = f2bf(val);
        if (sel == 0)
          Q[(size_t)((bb * 16 + h) * 1024 + s + r) * 64 + d] = ob;
        else if (sel == 1)
          K[(size_t)((bb * 16 + h) * 1024 + s + r) * 64 + d] = ob;
        else
          Vt[(size_t)((bb * 16 + h) * 64 + d) * 1024 + s + r] = ob;
      }
    }
  }
}

// ---------------- flash attention, swapped-QK orientation ----------------
// grid = B*H*(S/64) = 1024 blocks; 4 waves/block, each wave 16 q-rows.
// S = mfma(K,Q) -> C[key][q]: key axis in regs (4) x lane-groups (4),
// q = lane&15. Row-reduce = 15 local fmax + 2 shuffles. P redistributed
// to PV A-fragments via 8 bpermute + 4 selects per 32 keys (no LDS).
__global__ __launch_bounds__(256) void attn(
    const ushort* __restrict__ Q,    // [B*H][S][64], pre-scaled by 0.125
    const ushort* __restrict__ K,    // [B*H][S][64]
    const ushort* __restrict__ Vt,   // [B*H][64][S]
    const float* __restrict__ mask,  // [B][S]
    float* __restrict__ out)         // [B][S][1024]
{
  __shared__ float mask_s[SS];               // 4 KB

  int blk = blockIdx.x;
  int bh = blk >> 4;
  int qt = blk & 15;
  int b = bh >> 4, h = bh & 15;
  int tid = threadIdx.x, wave = tid >> 6, lane = tid & 63;
  int g = lane >> 4, c = lane & 15;
  int q0 = qt * 64 + wave * 16;

  for (int i = tid; i < SS; i += 256) mask_s[i] = mask[b * SS + i];
  __syncthreads();

  const ushort* Qb = Q + (size_t)bh * SS * 64;
  const ushort* Kb = K + (size_t)bh * SS * 64;
  const ushort* Vb = Vt + (size_t)bh * 64 * SS;

  // Q fragments (B operand): B[k=g*8+j][col=c] == Q[q0+c][g*8+j]
  bf16x8 qf0 = *(const bf16x8*)(Qb + (q0 + c) * 64 + g * 8);
  bf16x8 qf1 = *(const bf16x8*)(Qb + (q0 + c) * 64 + 32 + g * 8);

  f32x4 o[4] = {};                   // O[q=4g+r][d=c4*16+c]
  float mrow = 0.f, lrow = 0.f;      // stats for q=c (replicated over g)

  // bpermute byte addrs for P redistribution (constant per lane)
  int addrA = ((((g & 1) << 1) + 0) * 16 + c) << 2;
  int addrB = ((((g & 1) << 1) + 1) * 16 + c) << 2;
  bool hiSel = (g >= 2);

  for (int kv = 0; kv < SS; kv += 64) {
    // S tiles t=0..3: keys kv+16t .. kv+16t+15; C[key][q]
    f32x4 s[4];
    #pragma unroll
    for (int t = 0; t < 4; ++t) {
      f32x4 z = {0.f, 0.f, 0.f, 0.f};
      bf16x8 ka = *(const bf16x8*)(Kb + (size_t)(kv + t * 16 + c) * 64 + g * 8);
      bf16x8 kb = *(const bf16x8*)(Kb + (size_t)(kv + t * 16 + c) * 64 + 32 + g * 8);
      z = __builtin_amdgcn_mfma_f32_16x16x32_bf16(ka, qf0, z, 0, 0, 0);
      z = __builtin_amdgcn_mfma_f32_16x16x32_bf16(kb, qf1, z, 0, 0, 0);
      s[t] = z;
    }
    // mask add: lane (g,c) reg r of tile t holds key kv+16t+4g+r
    #pragma unroll
    for (int t = 0; t < 4; ++t) {
      f32x4 mk = *(const f32x4*)(&mask_s[kv + t * 16 + g * 4]);
      s[t] += mk;
    }
    // running max for q=c
    float mx = s[0][0];
    #pragma unroll
    for (int t = 0; t < 4; ++t)
      #pragma unroll
      for (int r = 0; r < 4; ++r) mx = fmaxf(mx, s[t][r]);
    mx = fmaxf(mx, __shfl_xor(mx, 16));
    mx = fmaxf(mx, __shfl_xor(mx, 32));

    if (!__all(mx <= mrow + 8.f)) {       // defer-max: rare with sane data
      float mn = fmaxf(mrow, mx);
      float sc = __expf(mrow - mn);
      mrow = mn;
      lrow *= sc;
      #pragma unroll
      for (int r = 0; r < 4; ++r) {
        float scq = __shfl(sc, g * 4 + r);   // sc for q=4g+r
        #pragma unroll
        for (int c4 = 0; c4 < 4; ++c4) o[c4][r] *= scq;
      }
    }

    // P = exp(S - m), row sum
    f32x4 p[4];
    float rs = 0.f;
    #pragma unroll
    for (int t = 0; t < 4; ++t)
      #pragma unroll
      for (int r = 0; r < 4; ++r) {
        float e = __expf(s[t][r] - mrow);
        p[t][r] = e;
        rs += e;
      }
    rs += __shfl_xor(rs, 16);
    rs += __shfl_xor(rs, 32);
    lrow += rs;

    // per 32-key half: pack to bf16, redistribute into PV A-frag, PV MFMA
    #pragma unroll
    for (int hh = 0; hh < 2; ++hh) {
      unsigned W0 = pack2(p[2 * hh][0], p[2 * hh][1]);
      unsigned W1 = pack2(p[2 * hh][2], p[2 * hh][3]);
      unsigned W2 = pack2(p[2 * hh + 1][0], p[2 * hh + 1][1]);
      unsigned W3 = pack2(p[2 * hh + 1][2], p[2 * hh + 1][3]);
      int w0l = __builtin_amdgcn_ds_bpermute(addrA, (int)W0);
      int w0h = __builtin_amdgcn_ds_bpermute(addrA, (int)W2);
      int w1l = __builtin_amdgcn_ds_bpermute(addrA, (int)W1);
      int w1h = __builtin_amdgcn_ds_bpermute(addrA, (int)W3);
      int w2l = __builtin_amdgcn_ds_bpermute(addrB, (int)W0);
      int w2h = __builtin_amdgcn_ds_bpermute(addrB, (int)W2);
      int w3l = __builtin_amdgcn_ds_bpermute(addrB, (int)W1);
      int w3h = __builtin_amdgcn_ds_bpermute(addrB, (int)W3);
      union { unsigned u[4]; bf16x8 v; } aw;
      aw.u[0] = (unsigned)(hiSel ? w0h : w0l);
      aw.u[1] = (unsigned)(hiSel ? w1h : w1l);
      aw.u[2] = (unsigned)(hiSel ? w2h : w2l);
      aw.u[3] = (unsigned)(hiSel ? w3h : w3l);
      bf16x8 pf = aw.v;
      #pragma unroll
      for (int c4 = 0; c4 < 4; ++c4) {
        bf16x8 vf = *(const bf16x8*)(Vb + (size_t)(c4 * 16 + c) * SS + kv + hh * 32 + g * 8);
        o[c4] = __builtin_amdgcn_mfma_f32_16x16x32_bf16(pf, vf, o[c4], 0, 0, 0);
      }
    }
  }

  float lr[4];
  #pragma unroll
  for (int r = 0; r < 4; ++r)
    lr[r] = 1.0f / __shfl(lrow, g * 4 + r);   // lrow for q=4g+r

  #pragma unroll
  for (int c4 = 0; c4 < 4; ++c4) {
    #pragma unroll
    for (int r = 0; r < 4; ++r) {
      out[(size_t)(b * SS + q0 + g * 4 + r) * 1024 + h * 64 + c4 * 16 + c] =
          o[c4][r] * lr[r];
    }
  }
}

extern "C" void kernel_launch(void* const* d_in, const int* in_sizes, int n_in,
                              void* d_out, int out_size, void* d_ws, size_t ws_size,
                              hipStream_t stream) {
  const float* hs   = (const float*)d_in[0];
  const float* mask = (const float*)d_in[1];
  const float* Wq   = (const float*)d_in[2];
  const float* bq   = (const float*)d_in[3];
  const float* Wk   = (const float*)d_in[4];
  const float* bk   = (const float*)d_in[5];
  const float* Wv   = (const float*)d_in[6];
  const float* bv   = (const float*)d_in[7];
  float* out = (float*)d_out;

  char* ws = (char*)d_ws;
  ushort* Xb = (ushort*)(ws);                    // 8 MB  [4096][1024]
  ushort* Wb = (ushort*)(ws + (8u  << 20));      // 6 MB  [3072][1024]
  ushort* Qp = (ushort*)(ws + (14u << 20));      // 8 MB  [64][1024][64]
  ushort* Kp = (ushort*)(ws + (22u << 20));      // 8 MB  [64][1024][64]
  ushort* Vt = (ushort*)(ws + (30u << 20));      // 8 MB  [64][64][1024]

  cvt_all<<<7168, 256, 0, stream>>>((const float4*)hs, (const float4*)Wq,
                                    (const float4*)Wk, (const float4*)Wv,
                                    (ushort4*)Xb, (ushort4*)Wb);
  qkv_gemm<<<768, 256, 0, stream>>>(Xb, Wb, bq, bk, bv, Qp, Kp, Vt);
  attn<<<1024, 256, 0, stream>>>(Qp, Kp, Vt, mask, out);
}

// Round 3
// 98.908 us; speedup vs baseline: 1.7455x; 1.7325x over previous
//
#include <hip/hip_runtime.h>
#include <hip/hip_bf16.h>
#include <stdint.h>

#define NH 16
#define HID 1024
#define HD 64
#define NB 4
#define SS 1024
#define MTOT (NB*SS)   // 4096

typedef __attribute__((ext_vector_type(8))) short bf16x8;
typedef __attribute__((ext_vector_type(4))) float f32x4;

__device__ __forceinline__ unsigned short f2bf(float f) {
  union { float f; unsigned u; } v; v.f = f;
  unsigned u = v.u;
  return (unsigned short)((u + 0x7FFFu + ((u >> 16) & 1u)) >> 16);
}

__device__ __forceinline__ unsigned pack2(float lo, float hi) {
  return (unsigned)f2bf(lo) | ((unsigned)f2bf(hi) << 16);
}

__device__ __forceinline__ void async16(void* lds, const void* g) {
  __builtin_amdgcn_global_load_lds(
      (const __attribute__((address_space(1))) unsigned*)g,
      (__attribute__((address_space(3))) unsigned*)lds, 16, 0, 0);
}

// ---------------- fp32 -> bf16 conversion of X and W ----------------
__global__ void cvt_all(const float4* __restrict__ X,
                        const float4* __restrict__ Wq,
                        const float4* __restrict__ Wk,
                        const float4* __restrict__ Wv,
                        ushort4* __restrict__ Xb,
                        ushort4* __restrict__ Wb) {
  int i = blockIdx.x * 256 + threadIdx.x;   // 1835008 total
  const float4* src; ushort4* dst; int idx;
  if (i < (MTOT * HID / 4)) {               // 1048576 float4 of X
    src = X; dst = Xb; idx = i;
  } else {
    int j = i - (MTOT * HID / 4);           // 786432 float4 of W
    int sel = j >> 18;                      // 262144 float4 per W
    idx = j & 262143;
    src = (sel == 0) ? Wq : (sel == 1) ? Wk : Wv;
    dst = Wb + (size_t)sel * 262144;
  }
  float4 v = src[idx];
  ushort4 o;
  o.x = f2bf(v.x); o.y = f2bf(v.y); o.z = f2bf(v.z); o.w = f2bf(v.w);
  dst[idx] = o;
}

// ---------------- fused QKV projection GEMM ----------------
__global__ __launch_bounds__(256) void qkv_gemm(
    const ushort* __restrict__ Xb,    // [4096][1024] bf16
    const ushort* __restrict__ Wb,    // [3072][1024] bf16 (Wq|Wk|Wv)
    const float* __restrict__ bq,
    const float* __restrict__ bk,
    const float* __restrict__ bv,
    ushort* __restrict__ Q,           // [B*H][S][64]
    ushort* __restrict__ K,           // [B*H][S][64]
    ushort* __restrict__ Vt)          // [B*H][64][S]
{
  __shared__ ushort Al[128 * 64];     // 16 KB
  __shared__ ushort Bl[128 * 64];     // 16 KB

  int bid = blockIdx.x;               // 768 blocks
  int swz = (bid & 7) * 96 + (bid >> 3);  // XCD-aware swizzle (768 % 8 == 0)
  const int nbn = 3072 / 128;         // 24
  int bm = swz / nbn, bn = swz % nbn;
  int m0 = bm * 128, n0 = bn * 128;

  int tid = threadIdx.x;
  int wave = tid >> 6, lane = tid & 63;
  int g = lane >> 4, c = lane & 15;
  int wr = wave >> 1, wc = wave & 1;  // 2x2 waves, each 64x64 output

  const ushort* Asrc = Xb + (size_t)(m0 + (tid >> 3)) * 1024 + (tid & 7) * 8;
  const ushort* Bsrc = Wb + (size_t)(n0 + (tid >> 3)) * 1024 + (tid & 7) * 8;

  f32x4 acc[4][4] = {};

  for (int ks = 0; ks < 16; ++ks) {
    int k0 = ks * 64;
    __syncthreads();
    #pragma unroll
    for (int i = 0; i < 4; ++i) {
      async16((char*)Al + i * 4096 + wave * 1024, Asrc + (size_t)i * 32 * 1024 + k0);
      async16((char*)Bl + i * 4096 + wave * 1024, Bsrc + (size_t)i * 32 * 1024 + k0);
    }
    __syncthreads();
    #pragma unroll
    for (int kk = 0; kk < 2; ++kk) {
      bf16x8 a[4], b[4];
      #pragma unroll
      for (int m = 0; m < 4; ++m)
        a[m] = *(const bf16x8*)((const char*)Al + (wr * 64 + m * 16 + c) * 128 + kk * 64 + g * 16);
      #pragma unroll
      for (int n = 0; n < 4; ++n)
        b[n] = *(const bf16x8*)((const char*)Bl + (wc * 64 + n * 16 + c) * 128 + kk * 64 + g * 16);
      #pragma unroll
      for (int m = 0; m < 4; ++m)
        #pragma unroll
        for (int n = 0; n < 4; ++n)
          acc[m][n] = __builtin_amdgcn_mfma_f32_16x16x32_bf16(a[m], b[n], acc[m][n], 0, 0, 0);
    }
  }

  int sel = n0 >> 10;
  const float* bp = (sel == 0) ? bq : (sel == 1) ? bk : bv;
  float scl = (sel == 0) ? 0.125f : 1.0f;

  #pragma unroll
  for (int n = 0; n < 4; ++n) {
    int nn = (n0 & 1023) + wc * 64 + n * 16 + c;
    float bias = bp[nn];
    int h = nn >> 6, d = nn & 63;
    #pragma unroll
    for (int m = 0; m < 4; ++m) {
      int rowg = m0 + wr * 64 + m * 16 + g * 4;
      int bb = rowg >> 10;
      int s = rowg & 1023;
      #pragma unroll
      for (int r = 0; r < 4; ++r) {
        float val = (acc[m][n][r] + bias) * scl;
        unsigned short ob = f2bf(val);
        if (sel == 0)
          Q[(size_t)((bb * 16 + h) * 1024 + s + r) * 64 + d] = ob;
        else if (sel == 1)
          K[(size_t)((bb * 16 + h) * 1024 + s + r) * 64 + d] = ob;
        else
          Vt[(size_t)((bb * 16 + h) * 64 + d) * 1024 + s + r] = ob;
      }
    }
  }
}

// ---------------- flash attention ----------------
// grid = 1024 blocks; XCD head-affinity swizzle (8 heads/XCD -> K/V L2-resident).
// 4 waves/block, wave handles 16 q-rows. K/V staged to LDS double-buffered via
// global_load_lds (pre-swizzled source, XOR bank swizzle), counted vmcnt.
__global__ __launch_bounds__(256) void attn(
    const ushort* __restrict__ Q,    // [B*H][S][64], pre-scaled by 0.125
    const ushort* __restrict__ K,    // [B*H][S][64]
    const ushort* __restrict__ Vt,   // [B*H][64][S]
    const float* __restrict__ mask,  // [B][S]
    float* __restrict__ out)         // [B][S][1024]
{
  __shared__ float mask_s[SS];                                   // 4 KB
  __shared__ __attribute__((aligned(16))) char kv_lds[2][16384]; // 32 KB: [K 8K][V 8K]

  int blk = blockIdx.x;
  // XCD head-affinity: blocks with blk%8==x land on XCD x (round-robin dispatch).
  int xcd = blk & 7;
  int j = blk >> 3;               // 0..127
  int bh = xcd * 8 + (j >> 4);    // 8 heads per XCD; 16 blocks per head, same XCD
  int qt = j & 15;
  int b = bh >> 4, h = bh & 15;
  int tid = threadIdx.x, wave = tid >> 6, lane = tid & 63;
  int g = lane >> 4, c = lane & 15;
  int q0 = qt * 64 + wave * 16;

  for (int i = tid; i < SS; i += 256) mask_s[i] = mask[b * SS + i];
  __syncthreads();

  const ushort* Qb = Q + (size_t)bh * SS * 64;
  const ushort* Kb = K + (size_t)bh * SS * 64;
  const ushort* Vb = Vt + (size_t)bh * 64 * SS;

  // Q fragments (B operand): B[k=g*8+j][col=c] == Q[q0+c][g*8+j]
  bf16x8 qf0 = *(const bf16x8*)(Qb + (q0 + c) * 64 + g * 8);
  bf16x8 qf1 = *(const bf16x8*)(Qb + (q0 + c) * 64 + 32 + g * 8);

  // --- staging pointers: waves 0,1 stage K tile (8KB), waves 2,3 stage V tile.
  // LDS write is linear (base + lane*16); bank-swizzle achieved by XOR on the
  // GLOBAL chunk index (chunk' = chunk ^ (row&7)); compute reads with same XOR.
  int srow = lane >> 3;           // 0..7 (== row&7 within each 8-row group)
  int schunk = lane & 7;
  const ushort* sptr[4];
  int soff[4];
  #pragma unroll
  for (int j2 = 0; j2 < 4; ++j2) {
    soff[j2] = wave * 4096 + j2 * 1024;
    if (wave < 2) {
      int row = wave * 32 + j2 * 8 + srow;            // key row in tile
      sptr[j2] = Kb + (size_t)row * 64 + ((schunk ^ srow) << 3);
    } else {
      int d = (wave - 2) * 32 + j2 * 8 + srow;        // dim row in tile
      sptr[j2] = Vb + (size_t)d * SS + ((schunk ^ srow) << 3);
    }
  }
  const int sstep = (wave < 2) ? 64 * 64 : 64;        // elements per 64-key tile

#define STAGE(bufidx) do {                              \
    char* lb_ = kv_lds[bufidx];                         \
    async16(lb_ + soff[0], sptr[0]);                    \
    async16(lb_ + soff[1], sptr[1]);                    \
    async16(lb_ + soff[2], sptr[2]);                    \
    async16(lb_ + soff[3], sptr[3]);                    \
    sptr[0] += sstep; sptr[1] += sstep;                 \
    sptr[2] += sstep; sptr[3] += sstep;                 \
  } while (0)

  f32x4 o[4] = {};                   // O[q=4g+r][d=c4*16+c]
  float mrow = 0.f, lrow = 0.f;      // stats for q=c (replicated over g)

  // bpermute byte addrs for P redistribution (constant per lane)
  int addrA = ((((g & 1) << 1) + 0) * 16 + c) << 2;
  int addrB = ((((g & 1) << 1) + 1) * 16 + c) << 2;
  bool hiSel = (g >= 2);

  int cswz = c & 7;

  STAGE(0);                         // prologue: tile 0 in flight

  for (int it = 0; it < 16; ++it) {
    int cur = it & 1;
    if (it < 15) {
      STAGE(cur ^ 1);               // next tile: 4 loads stay in flight
      asm volatile("s_waitcnt vmcnt(4)" ::: "memory");
    } else {
      asm volatile("s_waitcnt vmcnt(0)" ::: "memory");
    }
    __builtin_amdgcn_sched_barrier(0);
    __builtin_amdgcn_s_barrier();   // all waves' cur-tile staging complete
    __builtin_amdgcn_sched_barrier(0);

    const char* kb0 = kv_lds[cur];
    const char* vb0 = kv_lds[cur] + 8192;

    // QK^T: S tiles t=0..3 -> C[key][q]
    f32x4 s[4];
    __builtin_amdgcn_s_setprio(1);
    #pragma unroll
    for (int t = 0; t < 4; ++t) {
      f32x4 z = {0.f, 0.f, 0.f, 0.f};
      bf16x8 ka = *(const bf16x8*)(kb0 + (t * 16 + c) * 128 + ((g ^ cswz) << 4));
      bf16x8 kB = *(const bf16x8*)(kb0 + (t * 16 + c) * 128 + (((4 + g) ^ cswz) << 4));
      z = __builtin_amdgcn_mfma_f32_16x16x32_bf16(ka, qf0, z, 0, 0, 0);
      z = __builtin_amdgcn_mfma_f32_16x16x32_bf16(kB, qf1, z, 0, 0, 0);
      s[t] = z;
    }
    __builtin_amdgcn_s_setprio(0);

    // mask add: lane (g,c) reg r of tile t holds key it*64+16t+4g+r
    #pragma unroll
    for (int t = 0; t < 4; ++t) {
      f32x4 mk = *(const f32x4*)(&mask_s[it * 64 + t * 16 + g * 4]);
      s[t] += mk;
    }
    // running max for q=c
    float mx = s[0][0];
    #pragma unroll
    for (int t = 0; t < 4; ++t)
      #pragma unroll
      for (int r = 0; r < 4; ++r) mx = fmaxf(mx, s[t][r]);
    mx = fmaxf(mx, __shfl_xor(mx, 16));
    mx = fmaxf(mx, __shfl_xor(mx, 32));

    if (!__all(mx <= mrow + 8.f)) {       // defer-max: rare with sane data
      float mn = fmaxf(mrow, mx);
      float sc = __expf(mrow - mn);
      mrow = mn;
      lrow *= sc;
      #pragma unroll
      for (int r = 0; r < 4; ++r) {
        float scq = __shfl(sc, g * 4 + r);   // sc for q=4g+r
        #pragma unroll
        for (int c4 = 0; c4 < 4; ++c4) o[c4][r] *= scq;
      }
    }

    // P = exp(S - m), row sum
    f32x4 p[4];
    float rs = 0.f;
    #pragma unroll
    for (int t = 0; t < 4; ++t)
      #pragma unroll
      for (int r = 0; r < 4; ++r) {
        float e = __expf(s[t][r] - mrow);
        p[t][r] = e;
        rs += e;
      }
    rs += __shfl_xor(rs, 16);
    rs += __shfl_xor(rs, 32);
    lrow += rs;

    // per 32-key half: pack to bf16, redistribute into PV A-frag, PV MFMA
    #pragma unroll
    for (int hh = 0; hh < 2; ++hh) {
      unsigned W0 = pack2(p[2 * hh][0], p[2 * hh][1]);
      unsigned W1 = pack2(p[2 * hh][2], p[2 * hh][3]);
      unsigned W2 = pack2(p[2 * hh + 1][0], p[2 * hh + 1][1]);
      unsigned W3 = pack2(p[2 * hh + 1][2], p[2 * hh + 1][3]);
      int w0l = __builtin_amdgcn_ds_bpermute(addrA, (int)W0);
      int w0h = __builtin_amdgcn_ds_bpermute(addrA, (int)W2);
      int w1l = __builtin_amdgcn_ds_bpermute(addrA, (int)W1);
      int w1h = __builtin_amdgcn_ds_bpermute(addrA, (int)W3);
      int w2l = __builtin_amdgcn_ds_bpermute(addrB, (int)W0);
      int w2h = __builtin_amdgcn_ds_bpermute(addrB, (int)W2);
      int w3l = __builtin_amdgcn_ds_bpermute(addrB, (int)W1);
      int w3h = __builtin_amdgcn_ds_bpermute(addrB, (int)W3);
      union { unsigned u[4]; bf16x8 v; } aw;
      aw.u[0] = (unsigned)(hiSel ? w0h : w0l);
      aw.u[1] = (unsigned)(hiSel ? w1h : w1l);
      aw.u[2] = (unsigned)(hiSel ? w2h : w2l);
      aw.u[3] = (unsigned)(hiSel ? w3h : w3l);
      bf16x8 pf = aw.v;
      __builtin_amdgcn_s_setprio(1);
      #pragma unroll
      for (int c4 = 0; c4 < 4; ++c4) {
        bf16x8 vf = *(const bf16x8*)(vb0 + (c4 * 16 + c) * 128 + (((hh * 4 + g) ^ cswz) << 4));
        o[c4] = __builtin_amdgcn_mfma_f32_16x16x32_bf16(pf, vf, o[c4], 0, 0, 0);
      }
      __builtin_amdgcn_s_setprio(0);
    }

    __builtin_amdgcn_sched_barrier(0);
    __builtin_amdgcn_s_barrier();   // all waves done reading buf[cur]
  }
#undef STAGE

  float lr[4];
  #pragma unroll
  for (int r = 0; r < 4; ++r)
    lr[r] = 1.0f / __shfl(lrow, g * 4 + r);   // lrow for q=4g+r

  #pragma unroll
  for (int c4 = 0; c4 < 4; ++c4) {
    #pragma unroll
    for (int r = 0; r < 4; ++r) {
      out[(size_t)(b * SS + q0 + g * 4 + r) * 1024 + h * 64 + c4 * 16 + c] =
          o[c4][r] * lr[r];
    }
  }
}

extern "C" void kernel_launch(void* const* d_in, const int* in_sizes, int n_in,
                              void* d_out, int out_size, void* d_ws, size_t ws_size,
                              hipStream_t stream) {
  const float* hs   = (const float*)d_in[0];
  const float* mask = (const float*)d_in[1];
  const float* Wq   = (const float*)d_in[2];
  const float* bq   = (const float*)d_in[3];
  const float* Wk   = (const float*)d_in[4];
  const float* bk   = (const float*)d_in[5];
  const float* Wv   = (const float*)d_in[6];
  const float* bv   = (const float*)d_in[7];
  float* out = (float*)d_out;

  char* ws = (char*)d_ws;
  ushort* Xb = (ushort*)(ws);                    // 8 MB  [4096][1024]
  ushort* Wb = (ushort*)(ws + (8u  << 20));      // 6 MB  [3072][1024]
  ushort* Qp = (ushort*)(ws + (14u << 20));      // 8 MB  [64][1024][64]
  ushort* Kp = (ushort*)(ws + (22u << 20));      // 8 MB  [64][1024][64]
  ushort* Vt = (ushort*)(ws + (30u << 20));      // 8 MB  [64][64][1024]

  cvt_all<<<7168, 256, 0, stream>>>((const float4*)hs, (const float4*)Wq,
                                    (const float4*)Wk, (const float4*)Wv,
                                    (ushort4*)Xb, (ushort4*)Wb);
  qkv_gemm<<<768, 256, 0, stream>>>(Xb, Wb, bq, bk, bv, Qp, Kp, Vt);
  attn<<<1024, 256, 0, stream>>>(Qp, Kp, Vt, mask, out);
}

// Round 4
// 87.987 us; speedup vs baseline: 1.9622x; 1.1241x over previous
//
#include <hip/hip_runtime.h>
#include <hip/hip_bf16.h>
#include <stdint.h>

#define NH 16
#define HID 1024
#define HD 64
#define NB 4
#define SS 1024
#define MTOT (NB*SS)   // 4096

typedef __attribute__((ext_vector_type(8))) short bf16x8;
typedef __attribute__((ext_vector_type(4))) float f32x4;
typedef __attribute__((ext_vector_type(16))) float f32x16;

#define LOG2E 1.44269504088896f

__device__ __forceinline__ unsigned short f2bf(float f) {
  union { float f; unsigned u; } v; v.f = f;
  unsigned u = v.u;
  return (unsigned short)((u + 0x7FFFu + ((u >> 16) & 1u)) >> 16);
}

__device__ __forceinline__ unsigned cvtpk(float lo, float hi) {
  unsigned r;
  asm("v_cvt_pk_bf16_f32 %0, %1, %2" : "=v"(r) : "v"(lo), "v"(hi));
  return r;
}

__device__ __forceinline__ void pl32swap(unsigned &a, unsigned &b) {
  asm("v_permlane32_swap_b32 %0, %1" : "+v"(a), "+v"(b));
}

__device__ __forceinline__ float exp2fast(float x) {
  float r;
  asm("v_exp_f32 %0, %1" : "=v"(r) : "v"(x));
  return r;
}

__device__ __forceinline__ void async16(void* lds, const void* g) {
  __builtin_amdgcn_global_load_lds(
      (const __attribute__((address_space(1))) unsigned*)g,
      (__attribute__((address_space(3))) unsigned*)lds, 16, 0, 0);
}

// ---------------- fp32 -> bf16 conversion of X and W ----------------
__global__ void cvt_all(const float4* __restrict__ X,
                        const float4* __restrict__ Wq,
                        const float4* __restrict__ Wk,
                        const float4* __restrict__ Wv,
                        ushort4* __restrict__ Xb,
                        ushort4* __restrict__ Wb) {
  int i = blockIdx.x * 256 + threadIdx.x;   // 1835008 total
  const float4* src; ushort4* dst; int idx;
  if (i < (MTOT * HID / 4)) {
    src = X; dst = Xb; idx = i;
  } else {
    int j = i - (MTOT * HID / 4);
    int sel = j >> 18;
    idx = j & 262143;
    src = (sel == 0) ? Wq : (sel == 1) ? Wk : Wv;
    dst = Wb + (size_t)sel * 262144;
  }
  float4 v = src[idx];
  ushort4 o;
  o.x = f2bf(v.x); o.y = f2bf(v.y); o.z = f2bf(v.z); o.w = f2bf(v.w);
  dst[idx] = o;
}

// ---------------- fused QKV projection GEMM ----------------
// Q pre-scaled by 0.125*log2(e) so attention softmax runs in exp2 domain.
__global__ __launch_bounds__(256) void qkv_gemm(
    const ushort* __restrict__ Xb,    // [4096][1024] bf16
    const ushort* __restrict__ Wb,    // [3072][1024] bf16 (Wq|Wk|Wv)
    const float* __restrict__ bq,
    const float* __restrict__ bk,
    const float* __restrict__ bv,
    ushort* __restrict__ Q,           // [B*H][S][64]
    ushort* __restrict__ K,           // [B*H][S][64]
    ushort* __restrict__ Vt)          // [B*H][64][S]
{
  __shared__ ushort Al[128 * 64];
  __shared__ ushort Bl[128 * 64];

  int bid = blockIdx.x;               // 768 blocks
  int swz = (bid & 7) * 96 + (bid >> 3);
  const int nbn = 3072 / 128;         // 24
  int bm = swz / nbn, bn = swz % nbn;
  int m0 = bm * 128, n0 = bn * 128;

  int tid = threadIdx.x;
  int wave = tid >> 6, lane = tid & 63;
  int g = lane >> 4, c = lane & 15;
  int wr = wave >> 1, wc = wave & 1;

  const ushort* Asrc = Xb + (size_t)(m0 + (tid >> 3)) * 1024 + (tid & 7) * 8;
  const ushort* Bsrc = Wb + (size_t)(n0 + (tid >> 3)) * 1024 + (tid & 7) * 8;

  f32x4 acc[4][4] = {};

  for (int ks = 0; ks < 16; ++ks) {
    int k0 = ks * 64;
    __syncthreads();
    #pragma unroll
    for (int i = 0; i < 4; ++i) {
      async16((char*)Al + i * 4096 + wave * 1024, Asrc + (size_t)i * 32 * 1024 + k0);
      async16((char*)Bl + i * 4096 + wave * 1024, Bsrc + (size_t)i * 32 * 1024 + k0);
    }
    __syncthreads();
    #pragma unroll
    for (int kk = 0; kk < 2; ++kk) {
      bf16x8 a[4], b[4];
      #pragma unroll
      for (int m = 0; m < 4; ++m)
        a[m] = *(const bf16x8*)((const char*)Al + (wr * 64 + m * 16 + c) * 128 + kk * 64 + g * 16);
      #pragma unroll
      for (int n = 0; n < 4; ++n)
        b[n] = *(const bf16x8*)((const char*)Bl + (wc * 64 + n * 16 + c) * 128 + kk * 64 + g * 16);
      #pragma unroll
      for (int m = 0; m < 4; ++m)
        #pragma unroll
        for (int n = 0; n < 4; ++n)
          acc[m][n] = __builtin_amdgcn_mfma_f32_16x16x32_bf16(a[m], b[n], acc[m][n], 0, 0, 0);
    }
  }

  int sel = n0 >> 10;
  const float* bp = (sel == 0) ? bq : (sel == 1) ? bk : bv;
  float scl = (sel == 0) ? 0.125f * LOG2E : 1.0f;

  #pragma unroll
  for (int n = 0; n < 4; ++n) {
    int nn = (n0 & 1023) + wc * 64 + n * 16 + c;
    float bias = bp[nn];
    int h = nn >> 6, d = nn & 63;
    #pragma unroll
    for (int m = 0; m < 4; ++m) {
      int rowg = m0 + wr * 64 + m * 16 + g * 4;
      int bb = rowg >> 10;
      int s = rowg & 1023;
      #pragma unroll
      for (int r = 0; r < 4; ++r) {
        float val = (acc[m][n][r] + bias) * scl;
        unsigned short ob = f2bf(val);
        if (sel == 0)
          Q[(size_t)((bb * 16 + h) * 1024 + s + r) * 64 + d] = ob;
        else if (sel == 1)
          K[(size_t)((bb * 16 + h) * 1024 + s + r) * 64 + d] = ob;
        else
          Vt[(size_t)((bb * 16 + h) * 64 + d) * 1024 + s + r] = ob;
      }
    }
  }
}

// Build two PV A-fragments (keys 16k̂..16k̂+15, k̂=0,1 within a 32-key C-tile)
// from the 16 P values (C-layout) — 8 cvt_pk + 4 permlane32_swap, no LDS.
__device__ __forceinline__ void build_pa(const f32x16& p, bf16x8& pa0, bf16x8& pa1) {
  unsigned W0 = cvtpk(p[0],  p[1]);
  unsigned W1 = cvtpk(p[2],  p[3]);
  unsigned W2 = cvtpk(p[4],  p[5]);
  unsigned W3 = cvtpk(p[6],  p[7]);
  unsigned W4 = cvtpk(p[8],  p[9]);
  unsigned W5 = cvtpk(p[10], p[11]);
  unsigned W6 = cvtpk(p[12], p[13]);
  unsigned W7 = cvtpk(p[14], p[15]);
  pl32swap(W0, W2);   // W0 -> dword0, W2 -> dword2 of pa0
  pl32swap(W1, W3);   // W1 -> dword1, W3 -> dword3
  pl32swap(W4, W6);
  pl32swap(W5, W7);
  union { unsigned u[4]; bf16x8 v; } a0, a1;
  a0.u[0] = W0; a0.u[1] = W1; a0.u[2] = W2; a0.u[3] = W3;
  a1.u[0] = W4; a1.u[1] = W5; a1.u[2] = W6; a1.u[3] = W7;
  pa0 = a0.v; pa1 = a1.v;
}

// ---------------- flash attention, 32x32 swapped orientation ----------------
// grid = 512; block = 4 waves x 32 q-rows = 128 q-rows. XCD head-affinity.
// S^T = mfma32(K,Q): C[key][q], q = lane&31, key = (reg&3)+8*(reg>>2)+4*hi.
__global__ __launch_bounds__(256) void attn(
    const ushort* __restrict__ Q,    // [B*H][S][64], pre-scaled 0.125*log2e
    const ushort* __restrict__ K,    // [B*H][S][64]
    const ushort* __restrict__ Vt,   // [B*H][64][S]
    const float* __restrict__ mask,  // [B][S]
    float* __restrict__ out)         // [B][S][1024]
{
  __shared__ __attribute__((aligned(16))) char kv_lds[2][16384]; // [K 8K][V 8K]

  int blk = blockIdx.x;           // 512
  int xcd = blk & 7;
  int j = blk >> 3;               // 0..63
  int bh = xcd * 8 + (j >> 3);    // 8 heads per XCD
  int qt = j & 7;
  int b = bh >> 4, h = bh & 15;
  int tid = threadIdx.x, wave = tid >> 6, lane = tid & 63;
  int r31 = lane & 31, hi = lane >> 5;
  int rsw = r31 & 7;
  int hib = hi << 4;              // bpermute byte offset for 4*hi lanes
  int q0 = qt * 128 + wave * 32;

  const ushort* Qb = Q + (size_t)bh * SS * 64;
  const ushort* Kb = K + (size_t)bh * SS * 64;
  const ushort* Vb = Vt + (size_t)bh * 64 * SS;
  const float* mb = mask + b * SS;

  // Q fragments (B operand): lane (q=r31, hi) holds Q[q0+q][16*kp + 8*hi + e]
  bf16x8 qf[4];
  #pragma unroll
  for (int kp = 0; kp < 4; ++kp)
    qf[kp] = *(const bf16x8*)(Qb + (size_t)(q0 + r31) * 64 + kp * 16 + hi * 8);

  // --- staging: waves 0,1 -> K tile (8KB), waves 2,3 -> V tile (8KB).
  // LDS dest linear; bank swizzle via XOR on the GLOBAL chunk (chunk^row&7).
  int srow = lane >> 3;           // 0..7
  int schunk = lane & 7;
  const ushort* sptr[4];
  int soff[4];
  #pragma unroll
  for (int j2 = 0; j2 < 4; ++j2) {
    soff[j2] = wave * 4096 + j2 * 1024;
    if (wave < 2) {
      int row = wave * 32 + j2 * 8 + srow;
      sptr[j2] = Kb + (size_t)row * 64 + ((schunk ^ srow) << 3);
    } else {
      int d = (wave - 2) * 32 + j2 * 8 + srow;
      sptr[j2] = Vb + (size_t)d * SS + ((schunk ^ srow) << 3);
    }
  }
  const int sstep = (wave < 2) ? 64 * 64 : 64;

#define STAGE(bufidx) do {                              \
    char* lb_ = kv_lds[bufidx];                         \
    async16(lb_ + soff[0], sptr[0]);                    \
    async16(lb_ + soff[1], sptr[1]);                    \
    async16(lb_ + soff[2], sptr[2]);                    \
    async16(lb_ + soff[3], sptr[3]);                    \
    sptr[0] += sstep; sptr[1] += sstep;                 \
    sptr[2] += sstep; sptr[3] += sstep;                 \
  } while (0)

  f32x16 o0 = (f32x16)0.0f, o1 = (f32x16)0.0f;  // O[q][d-tile 0/1]
  float mrow = 0.f, lrow = 0.f;                  // stats for q = r31

  STAGE(0);

  for (int it = 0; it < 16; ++it) {
    int cur = it & 1;
    if (it < 15) {
      STAGE(cur ^ 1);
      asm volatile("s_waitcnt vmcnt(4)" ::: "memory");
    } else {
      asm volatile("s_waitcnt vmcnt(0)" ::: "memory");
    }
    __builtin_amdgcn_sched_barrier(0);
    __builtin_amdgcn_s_barrier();
    __builtin_amdgcn_sched_barrier(0);

    const char* kb0 = kv_lds[cur];
    const char* vb0 = kv_lds[cur] + 8192;

    // QK^T: two 32-key C-tiles
    f32x16 s0 = (f32x16)0.0f, s1 = (f32x16)0.0f;
    __builtin_amdgcn_s_setprio(1);
    #pragma unroll
    for (int kp = 0; kp < 4; ++kp) {
      int ch = (((kp << 1) | hi) ^ rsw) << 4;
      bf16x8 ka = *(const bf16x8*)(kb0 + r31 * 128 + ch);
      bf16x8 kc = *(const bf16x8*)(kb0 + (32 + r31) * 128 + ch);
      s0 = __builtin_amdgcn_mfma_f32_32x32x16_bf16(ka, qf[kp], s0, 0, 0, 0);
      s1 = __builtin_amdgcn_mfma_f32_32x32x16_bf16(kc, qf[kp], s1, 0, 0, 0);
    }
    __builtin_amdgcn_s_setprio(0);

    int kv = it * 64;
    // mask add in log2 domain (global read, L1-hot)
    #pragma unroll
    for (int sq = 0; sq < 4; ++sq) {
      f32x4 mk0 = *(const f32x4*)(mb + kv + sq * 8 + hi * 4);
      f32x4 mk1 = *(const f32x4*)(mb + kv + 32 + sq * 8 + hi * 4);
      #pragma unroll
      for (int r = 0; r < 4; ++r) {
        s0[sq * 4 + r] = fmaf(mk0[r], LOG2E, s0[sq * 4 + r]);
        s1[sq * 4 + r] = fmaf(mk1[r], LOG2E, s1[sq * 4 + r]);
      }
    }

    // row max over 32 held keys + 1 shuffle (lane q & q+32)
    float mx = s0[0];
    #pragma unroll
    for (int i = 1; i < 16; ++i) mx = fmaxf(mx, s0[i]);
    #pragma unroll
    for (int i = 0; i < 16; ++i) mx = fmaxf(mx, s1[i]);
    mx = fmaxf(mx, __shfl_xor(mx, 32));

    if (!__all(mx <= mrow + 11.5416f)) {   // defer-max (8 nats in log2)
      float mn = fmaxf(mrow, mx);
      float sc = exp2fast(mrow - mn);
      mrow = mn;
      lrow *= sc;
      #pragma unroll
      for (int i = 0; i < 16; ++i) {
        int qh = (i & 3) + 8 * (i >> 2);
        float scq = __uint_as_float((unsigned)__builtin_amdgcn_ds_bpermute(
            (qh << 2) + hib, (int)__float_as_uint(sc)));
        o0[i] *= scq; o1[i] *= scq;
      }
    }

    // P = exp2(S - m), accumulate row sum
    f32x16 p0, p1;
    float rs = 0.f;
    #pragma unroll
    for (int i = 0; i < 16; ++i) { float e = exp2fast(s0[i] - mrow); p0[i] = e; rs += e; }
    #pragma unroll
    for (int i = 0; i < 16; ++i) { float e = exp2fast(s1[i] - mrow); p1[i] = e; rs += e; }
    rs += __shfl_xor(rs, 32);
    lrow += rs;

    // PV: per 32-key tile, build A-frags in-register and MFMA
    #pragma unroll
    for (int T = 0; T < 2; ++T) {
      bf16x8 pa0, pa1;
      build_pa(T ? p1 : p0, pa0, pa1);
      __builtin_amdgcn_s_setprio(1);
      #pragma unroll
      for (int kh = 0; kh < 2; ++kh) {
        int kap = 2 * T + kh;                      // 16-key chunk index
        int ch = (((kap << 1) | hi) ^ rsw) << 4;
        bf16x8 va = *(const bf16x8*)(vb0 + r31 * 128 + ch);
        bf16x8 vc = *(const bf16x8*)(vb0 + (32 + r31) * 128 + ch);
        bf16x8 pf = kh ? pa1 : pa0;
        o0 = __builtin_amdgcn_mfma_f32_32x32x16_bf16(pf, va, o0, 0, 0, 0);
        o1 = __builtin_amdgcn_mfma_f32_32x32x16_bf16(pf, vc, o1, 0, 0, 0);
      }
      __builtin_amdgcn_s_setprio(0);
    }

    __builtin_amdgcn_sched_barrier(0);
    __builtin_amdgcn_s_barrier();   // all waves done reading buf[cur]
  }
#undef STAGE

  // normalize + store: lane (d=r31, hi), reg i -> q = (i&3)+8*(i>>2)+4*hi
  float inv = 1.0f / lrow;
  #pragma unroll
  for (int i = 0; i < 16; ++i) {
    int qh = (i & 3) + 8 * (i >> 2);
    float li = __uint_as_float((unsigned)__builtin_amdgcn_ds_bpermute(
        (qh << 2) + hib, (int)__float_as_uint(inv)));
    int row = q0 + qh + 4 * hi;
    float* op = out + (size_t)(b * SS + row) * 1024 + h * 64 + r31;
    op[0]  = o0[i] * li;
    op[32] = o1[i] * li;
  }
}

extern "C" void kernel_launch(void* const* d_in, const int* in_sizes, int n_in,
                              void* d_out, int out_size, void* d_ws, size_t ws_size,
                              hipStream_t stream) {
  const float* hs   = (const float*)d_in[0];
  const float* mask = (const float*)d_in[1];
  const float* Wq   = (const float*)d_in[2];
  const float* bq   = (const float*)d_in[3];
  const float* Wk   = (const float*)d_in[4];
  const float* bk   = (const float*)d_in[5];
  const float* Wv   = (const float*)d_in[6];
  const float* bv   = (const float*)d_in[7];
  float* out = (float*)d_out;

  char* ws = (char*)d_ws;
  ushort* Xb = (ushort*)(ws);                    // 8 MB  [4096][1024]
  ushort* Wb = (ushort*)(ws + (8u  << 20));      // 6 MB  [3072][1024]
  ushort* Qp = (ushort*)(ws + (14u << 20));      // 8 MB  [64][1024][64]
  ushort* Kp = (ushort*)(ws + (22u << 20));      // 8 MB  [64][1024][64]
  ushort* Vt = (ushort*)(ws + (30u << 20));      // 8 MB  [64][64][1024]

  cvt_all<<<7168, 256, 0, stream>>>((const float4*)hs, (const float4*)Wq,
                                    (const float4*)Wk, (const float4*)Wv,
                                    (ushort4*)Xb, (ushort4*)Wb);
  qkv_gemm<<<768, 256, 0, stream>>>(Xb, Wb, bq, bk, bv, Qp, Kp, Vt);
  attn<<<512, 256, 0, stream>>>(Qp, Kp, Vt, mask, out);
}

// Round 5
// 87.151 us; speedup vs baseline: 1.9810x; 1.0096x over previous
//
#include <hip/hip_runtime.h>
#include <hip/hip_bf16.h>
#include <stdint.h>

#define NH 16
#define HID 1024
#define HD 64
#define NB 4
#define SS 1024
#define MTOT (NB*SS)   // 4096

typedef __attribute__((ext_vector_type(8))) short bf16x8;
typedef __attribute__((ext_vector_type(4))) float f32x4;
typedef __attribute__((ext_vector_type(16))) float f32x16;

#define LOG2E 1.44269504088896f

__device__ __forceinline__ unsigned short f2bf(float f) {
  union { float f; unsigned u; } v; v.f = f;
  unsigned u = v.u;
  return (unsigned short)((u + 0x7FFFu + ((u >> 16) & 1u)) >> 16);
}

__device__ __forceinline__ unsigned cvtpk(float lo, float hi) {
  unsigned r;
  asm("v_cvt_pk_bf16_f32 %0, %1, %2" : "=v"(r) : "v"(lo), "v"(hi));
  return r;
}

__device__ __forceinline__ void pl32swap(unsigned &a, unsigned &b) {
  asm("v_permlane32_swap_b32 %0, %1" : "+v"(a), "+v"(b));
}

__device__ __forceinline__ float exp2fast(float x) {
  float r;
  asm("v_exp_f32 %0, %1" : "=v"(r) : "v"(x));
  return r;
}

__device__ __forceinline__ void async16(void* lds, const void* g) {
  __builtin_amdgcn_global_load_lds(
      (const __attribute__((address_space(1))) unsigned*)g,
      (__attribute__((address_space(3))) unsigned*)lds, 16, 0, 0);
}

// ---------------- fp32 -> bf16 conversion of X and W ----------------
__global__ void cvt_all(const float4* __restrict__ X,
                        const float4* __restrict__ Wq,
                        const float4* __restrict__ Wk,
                        const float4* __restrict__ Wv,
                        ushort4* __restrict__ Xb,
                        ushort4* __restrict__ Wb) {
  int i = blockIdx.x * 256 + threadIdx.x;   // 1835008 total
  const float4* src; ushort4* dst; int idx;
  if (i < (MTOT * HID / 4)) {
    src = X; dst = Xb; idx = i;
  } else {
    int j = i - (MTOT * HID / 4);
    int sel = j >> 18;
    idx = j & 262143;
    src = (sel == 0) ? Wq : (sel == 1) ? Wk : Wv;
    dst = Wb + (size_t)sel * 262144;
  }
  float4 v = src[idx];
  ushort4 o;
  o.x = f2bf(v.x); o.y = f2bf(v.y); o.z = f2bf(v.z); o.w = f2bf(v.w);
  dst[idx] = o;
}

// ---------------- fused QKV projection GEMM ----------------
// BK=32 double-buffered, counted vmcnt, XOR-swizzled LDS (T2/T3/T4/T5).
// Q pre-scaled by 0.125*log2(e) so attention softmax runs in exp2 domain.
__global__ __launch_bounds__(256) void qkv_gemm(
    const ushort* __restrict__ Xb,    // [4096][1024] bf16
    const ushort* __restrict__ Wb,    // [3072][1024] bf16 (Wq|Wk|Wv)
    const float* __restrict__ bq,
    const float* __restrict__ bk,
    const float* __restrict__ bv,
    ushort* __restrict__ Q,           // [B*H][S][64]
    ushort* __restrict__ K,           // [B*H][S][64]
    ushort* __restrict__ Vt)          // [B*H][64][S]
{
  __shared__ __attribute__((aligned(16))) ushort Al[2][128 * 32]; // 2x8KB
  __shared__ __attribute__((aligned(16))) ushort Bl[2][128 * 32]; // 2x8KB

  int bid = blockIdx.x;               // 768 blocks
  int swz = (bid & 7) * 96 + (bid >> 3);  // XCD swizzle (768 % 8 == 0)
  const int nbn = 3072 / 128;         // 24
  int bm = swz / nbn, bn = swz % nbn;
  int m0 = bm * 128, n0 = bn * 128;

  int tid = threadIdx.x;
  int wave = tid >> 6, lane = tid & 63;
  int g = lane >> 4, c = lane & 15;
  int wr = wave >> 1, wc = wave & 1;  // 2x2 waves, each 64x64 output

  // --- staging: per K-step each thread issues 2 A-loads + 2 B-loads (16B).
  // LDS dest linear; bank swizzle via XOR on the GLOBAL 16B-chunk index:
  // position p of row r holds logical chunk p ^ ((r>>1)&3)  (64B rows).
  int srow = tid >> 2;                // 0..63
  int schunk = tid & 3;
  int ssw = (srow >> 1) & 3;          // (row>>1)&3 invariant to +64
  const ushort* Asrc0 = Xb + (size_t)(m0 + srow) * 1024 + ((schunk ^ ssw) << 3);
  const ushort* Asrc1 = Xb + (size_t)(m0 + 64 + srow) * 1024 + ((schunk ^ ssw) << 3);
  const ushort* Bsrc0 = Wb + (size_t)(n0 + srow) * 1024 + ((schunk ^ ssw) << 3);
  const ushort* Bsrc1 = Wb + (size_t)(n0 + 64 + srow) * 1024 + ((schunk ^ ssw) << 3);
  int soff = srow * 64 + schunk * 16; // byte offset within 8KB half-tile

#define GSTAGE(bi) do {                                   \
    char* la_ = (char*)Al[bi]; char* lb_ = (char*)Bl[bi]; \
    async16(la_ + soff,        Asrc0);                    \
    async16(la_ + 4096 + soff, Asrc1);                    \
    async16(lb_ + soff,        Bsrc0);                    \
    async16(lb_ + 4096 + soff, Bsrc1);                    \
    Asrc0 += 32; Asrc1 += 32; Bsrc0 += 32; Bsrc1 += 32;   \
  } while (0)

  f32x4 acc[4][4] = {};
  int rsw = (c >> 1) & 3;             // read-side swizzle
  int ch = ((g ^ rsw) << 4);          // swizzled 16B chunk byte offset

  GSTAGE(0);                          // prologue: step 0 in flight

  for (int ks = 0; ks < 32; ++ks) {
    int cur = ks & 1;
    if (ks < 31) {
      GSTAGE(cur ^ 1);                // next step's 4 loads stay in flight
      asm volatile("s_waitcnt vmcnt(4)" ::: "memory");
    } else {
      asm volatile("s_waitcnt vmcnt(0)" ::: "memory");
    }
    __builtin_amdgcn_sched_barrier(0);
    __builtin_amdgcn_s_barrier();
    __builtin_amdgcn_sched_barrier(0);

    const char* la = (const char*)Al[cur];
    const char* lb = (const char*)Bl[cur];
    bf16x8 a[4], b[4];
    #pragma unroll
    for (int m = 0; m < 4; ++m)
      a[m] = *(const bf16x8*)(la + (wr * 64 + m * 16 + c) * 64 + ch);
    #pragma unroll
    for (int n = 0; n < 4; ++n)
      b[n] = *(const bf16x8*)(lb + (wc * 64 + n * 16 + c) * 64 + ch);
    __builtin_amdgcn_s_setprio(1);
    #pragma unroll
    for (int m = 0; m < 4; ++m)
      #pragma unroll
      for (int n = 0; n < 4; ++n)
        acc[m][n] = __builtin_amdgcn_mfma_f32_16x16x32_bf16(a[m], b[n], acc[m][n], 0, 0, 0);
    __builtin_amdgcn_s_setprio(0);

    __builtin_amdgcn_sched_barrier(0);
    __builtin_amdgcn_s_barrier();     // all waves done reading buf[cur]
  }
#undef GSTAGE

  int sel = n0 >> 10;
  const float* bp = (sel == 0) ? bq : (sel == 1) ? bk : bv;
  float scl = (sel == 0) ? 0.125f * LOG2E : 1.0f;

  #pragma unroll
  for (int n = 0; n < 4; ++n) {
    int nn = (n0 & 1023) + wc * 64 + n * 16 + c;
    float bias = bp[nn];
    int h = nn >> 6, d = nn & 63;
    #pragma unroll
    for (int m = 0; m < 4; ++m) {
      int rowg = m0 + wr * 64 + m * 16 + g * 4;
      int bb = rowg >> 10;
      int s = rowg & 1023;
      #pragma unroll
      for (int r = 0; r < 4; ++r) {
        float val = (acc[m][n][r] + bias) * scl;
        unsigned short ob = f2bf(val);
        if (sel == 0)
          Q[(size_t)((bb * 16 + h) * 1024 + s + r) * 64 + d] = ob;
        else if (sel == 1)
          K[(size_t)((bb * 16 + h) * 1024 + s + r) * 64 + d] = ob;
        else
          Vt[(size_t)((bb * 16 + h) * 64 + d) * 1024 + s + r] = ob;
      }
    }
  }
}

// Build two PV A-fragments from 16 P values (C-layout) — 8 cvt_pk + 4
// permlane32_swap, no LDS.
__device__ __forceinline__ void build_pa(const f32x16& p, bf16x8& pa0, bf16x8& pa1) {
  unsigned W0 = cvtpk(p[0],  p[1]);
  unsigned W1 = cvtpk(p[2],  p[3]);
  unsigned W2 = cvtpk(p[4],  p[5]);
  unsigned W3 = cvtpk(p[6],  p[7]);
  unsigned W4 = cvtpk(p[8],  p[9]);
  unsigned W5 = cvtpk(p[10], p[11]);
  unsigned W6 = cvtpk(p[12], p[13]);
  unsigned W7 = cvtpk(p[14], p[15]);
  pl32swap(W0, W2);
  pl32swap(W1, W3);
  pl32swap(W4, W6);
  pl32swap(W5, W7);
  union { unsigned u[4]; bf16x8 v; } a0, a1;
  a0.u[0] = W0; a0.u[1] = W1; a0.u[2] = W2; a0.u[3] = W3;
  a1.u[0] = W4; a1.u[1] = W5; a1.u[2] = W6; a1.u[3] = W7;
  pa0 = a0.v; pa1 = a1.v;
}

// ---------------- flash attention, 32x32 swapped orientation ----------------
__global__ __launch_bounds__(256) void attn(
    const ushort* __restrict__ Q,    // [B*H][S][64], pre-scaled 0.125*log2e
    const ushort* __restrict__ K,    // [B*H][S][64]
    const ushort* __restrict__ Vt,   // [B*H][64][S]
    const float* __restrict__ mask,  // [B][S]
    float* __restrict__ out)         // [B][S][1024]
{
  __shared__ __attribute__((aligned(16))) char kv_lds[2][16384]; // [K 8K][V 8K]

  int blk = blockIdx.x;           // 512
  int xcd = blk & 7;
  int j = blk >> 3;               // 0..63
  int bh = xcd * 8 + (j >> 3);    // 8 heads per XCD
  int qt = j & 7;
  int b = bh >> 4, h = bh & 15;
  int tid = threadIdx.x, wave = tid >> 6, lane = tid & 63;
  int r31 = lane & 31, hi = lane >> 5;
  int rsw = r31 & 7;
  int hib = hi << 4;
  int q0 = qt * 128 + wave * 32;

  const ushort* Qb = Q + (size_t)bh * SS * 64;
  const ushort* Kb = K + (size_t)bh * SS * 64;
  const ushort* Vb = Vt + (size_t)bh * 64 * SS;
  const float* mb = mask + b * SS;

  bf16x8 qf[4];
  #pragma unroll
  for (int kp = 0; kp < 4; ++kp)
    qf[kp] = *(const bf16x8*)(Qb + (size_t)(q0 + r31) * 64 + kp * 16 + hi * 8);

  int srow = lane >> 3;
  int schunk = lane & 7;
  const ushort* sptr[4];
  int soff[4];
  #pragma unroll
  for (int j2 = 0; j2 < 4; ++j2) {
    soff[j2] = wave * 4096 + j2 * 1024;
    if (wave < 2) {
      int row = wave * 32 + j2 * 8 + srow;
      sptr[j2] = Kb + (size_t)row * 64 + ((schunk ^ srow) << 3);
    } else {
      int d = (wave - 2) * 32 + j2 * 8 + srow;
      sptr[j2] = Vb + (size_t)d * SS + ((schunk ^ srow) << 3);
    }
  }
  const int sstep = (wave < 2) ? 64 * 64 : 64;

#define STAGE(bufidx) do {                              \
    char* lb_ = kv_lds[bufidx];                         \
    async16(lb_ + soff[0], sptr[0]);                    \
    async16(lb_ + soff[1], sptr[1]);                    \
    async16(lb_ + soff[2], sptr[2]);                    \
    async16(lb_ + soff[3], sptr[3]);                    \
    sptr[0] += sstep; sptr[1] += sstep;                 \
    sptr[2] += sstep; sptr[3] += sstep;                 \
  } while (0)

  f32x16 o0 = (f32x16)0.0f, o1 = (f32x16)0.0f;
  float mrow = 0.f, lrow = 0.f;

  STAGE(0);

  for (int it = 0; it < 16; ++it) {
    int cur = it & 1;
    if (it < 15) {
      STAGE(cur ^ 1);
      asm volatile("s_waitcnt vmcnt(4)" ::: "memory");
    } else {
      asm volatile("s_waitcnt vmcnt(0)" ::: "memory");
    }
    __builtin_amdgcn_sched_barrier(0);
    __builtin_amdgcn_s_barrier();
    __builtin_amdgcn_sched_barrier(0);

    const char* kb0 = kv_lds[cur];
    const char* vb0 = kv_lds[cur] + 8192;

    f32x16 s0 = (f32x16)0.0f, s1 = (f32x16)0.0f;
    __builtin_amdgcn_s_setprio(1);
    #pragma unroll
    for (int kp = 0; kp < 4; ++kp) {
      int ch = (((kp << 1) | hi) ^ rsw) << 4;
      bf16x8 ka = *(const bf16x8*)(kb0 + r31 * 128 + ch);
      bf16x8 kc = *(const bf16x8*)(kb0 + (32 + r31) * 128 + ch);
      s0 = __builtin_amdgcn_mfma_f32_32x32x16_bf16(ka, qf[kp], s0, 0, 0, 0);
      s1 = __builtin_amdgcn_mfma_f32_32x32x16_bf16(kc, qf[kp], s1, 0, 0, 0);
    }
    __builtin_amdgcn_s_setprio(0);

    int kv = it * 64;
    #pragma unroll
    for (int sq = 0; sq < 4; ++sq) {
      f32x4 mk0 = *(const f32x4*)(mb + kv + sq * 8 + hi * 4);
      f32x4 mk1 = *(const f32x4*)(mb + kv + 32 + sq * 8 + hi * 4);
      #pragma unroll
      for (int r = 0; r < 4; ++r) {
        s0[sq * 4 + r] = fmaf(mk0[r], LOG2E, s0[sq * 4 + r]);
        s1[sq * 4 + r] = fmaf(mk1[r], LOG2E, s1[sq * 4 + r]);
      }
    }

    float mx = s0[0];
    #pragma unroll
    for (int i = 1; i < 16; ++i) mx = fmaxf(mx, s0[i]);
    #pragma unroll
    for (int i = 0; i < 16; ++i) mx = fmaxf(mx, s1[i]);
    mx = fmaxf(mx, __shfl_xor(mx, 32));

    if (!__all(mx <= mrow + 11.5416f)) {
      float mn = fmaxf(mrow, mx);
      float sc = exp2fast(mrow - mn);
      mrow = mn;
      lrow *= sc;
      #pragma unroll
      for (int i = 0; i < 16; ++i) {
        int qh = (i & 3) + 8 * (i >> 2);
        float scq = __uint_as_float((unsigned)__builtin_amdgcn_ds_bpermute(
            (qh << 2) + hib, (int)__float_as_uint(sc)));
        o0[i] *= scq; o1[i] *= scq;
      }
    }

    f32x16 p0, p1;
    float rs = 0.f;
    #pragma unroll
    for (int i = 0; i < 16; ++i) { float e = exp2fast(s0[i] - mrow); p0[i] = e; rs += e; }
    #pragma unroll
    for (int i = 0; i < 16; ++i) { float e = exp2fast(s1[i] - mrow); p1[i] = e; rs += e; }
    rs += __shfl_xor(rs, 32);
    lrow += rs;

    #pragma unroll
    for (int T = 0; T < 2; ++T) {
      bf16x8 pa0, pa1;
      build_pa(T ? p1 : p0, pa0, pa1);
      __builtin_amdgcn_s_setprio(1);
      #pragma unroll
      for (int kh = 0; kh < 2; ++kh) {
        int kap = 2 * T + kh;
        int ch = (((kap << 1) | hi) ^ rsw) << 4;
        bf16x8 va = *(const bf16x8*)(vb0 + r31 * 128 + ch);
        bf16x8 vc = *(const bf16x8*)(vb0 + (32 + r31) * 128 + ch);
        bf16x8 pf = kh ? pa1 : pa0;
        o0 = __builtin_amdgcn_mfma_f32_32x32x16_bf16(pf, va, o0, 0, 0, 0);
        o1 = __builtin_amdgcn_mfma_f32_32x32x16_bf16(pf, vc, o1, 0, 0, 0);
      }
      __builtin_amdgcn_s_setprio(0);
    }

    __builtin_amdgcn_sched_barrier(0);
    __builtin_amdgcn_s_barrier();
  }
#undef STAGE

  float inv = 1.0f / lrow;
  #pragma unroll
  for (int i = 0; i < 16; ++i) {
    int qh = (i & 3) + 8 * (i >> 2);
    float li = __uint_as_float((unsigned)__builtin_amdgcn_ds_bpermute(
        (qh << 2) + hib, (int)__float_as_uint(inv)));
    int row = q0 + qh + 4 * hi;
    float* op = out + (size_t)(b * SS + row) * 1024 + h * 64 + r31;
    op[0]  = o0[i] * li;
    op[32] = o1[i] * li;
  }
}

extern "C" void kernel_launch(void* const* d_in, const int* in_sizes, int n_in,
                              void* d_out, int out_size, void* d_ws, size_t ws_size,
                              hipStream_t stream) {
  const float* hs   = (const float*)d_in[0];
  const float* mask = (const float*)d_in[1];
  const float* Wq   = (const float*)d_in[2];
  const float* bq   = (const float*)d_in[3];
  const float* Wk   = (const float*)d_in[4];
  const float* bk   = (const float*)d_in[5];
  const float* Wv   = (const float*)d_in[6];
  const float* bv   = (const float*)d_in[7];
  float* out = (float*)d_out;

  char* ws = (char*)d_ws;
  ushort* Xb = (ushort*)(ws);                    // 8 MB  [4096][1024]
  ushort* Wb = (ushort*)(ws + (8u  << 20));      // 6 MB  [3072][1024]
  ushort* Qp = (ushort*)(ws + (14u << 20));      // 8 MB  [64][1024][64]
  ushort* Kp = (ushort*)(ws + (22u << 20));      // 8 MB  [64][1024][64]
  ushort* Vt = (ushort*)(ws + (30u << 20));      // 8 MB  [64][64][1024]

  cvt_all<<<7168, 256, 0, stream>>>((const float4*)hs, (const float4*)Wq,
                                    (const float4*)Wk, (const float4*)Wv,
                                    (ushort4*)Xb, (ushort4*)Wb);
  qkv_gemm<<<768, 256, 0, stream>>>(Xb, Wb, bq, bk, bv, Qp, Kp, Vt);
  attn<<<512, 256, 0, stream>>>(Qp, Kp, Vt, mask, out);
}

// Round 6
// 85.829 us; speedup vs baseline: 2.0115x; 1.0154x over previous
//
#include <hip/hip_runtime.h>
#include <hip/hip_bf16.h>
#include <stdint.h>

#define NH 16
#define HID 1024
#define HD 64
#define NB 4
#define SS 1024
#define MTOT (NB*SS)   // 4096

typedef __attribute__((ext_vector_type(8))) short bf16x8;
typedef __attribute__((ext_vector_type(4))) float f32x4;
typedef __attribute__((ext_vector_type(16))) float f32x16;

#define LOG2E 1.44269504088896f

__device__ __forceinline__ unsigned short f2bf(float f) {
  union { float f; unsigned u; } v; v.f = f;
  unsigned u = v.u;
  return (unsigned short)((u + 0x7FFFu + ((u >> 16) & 1u)) >> 16);
}

__device__ __forceinline__ unsigned cvtpk(float lo, float hi) {
  unsigned r;
  asm("v_cvt_pk_bf16_f32 %0, %1, %2" : "=v"(r) : "v"(lo), "v"(hi));
  return r;
}

__device__ __forceinline__ void pl32swap(unsigned &a, unsigned &b) {
  asm("v_permlane32_swap_b32 %0, %1" : "+v"(a), "+v"(b));
}

__device__ __forceinline__ float exp2fast(float x) {
  float r;
  asm("v_exp_f32 %0, %1" : "=v"(r) : "v"(x));
  return r;
}

__device__ __forceinline__ void async16(void* lds, const void* g) {
  __builtin_amdgcn_global_load_lds(
      (const __attribute__((address_space(1))) unsigned*)g,
      (__attribute__((address_space(3))) unsigned*)lds, 16, 0, 0);
}

// ---------------- fp32 -> bf16 conversion of X and W ----------------
__global__ void cvt_all(const float4* __restrict__ X,
                        const float4* __restrict__ Wq,
                        const float4* __restrict__ Wk,
                        const float4* __restrict__ Wv,
                        ushort4* __restrict__ Xb,
                        ushort4* __restrict__ Wb) {
  int i = blockIdx.x * 256 + threadIdx.x;   // 1835008 total
  const float4* src; ushort4* dst; int idx;
  if (i < (MTOT * HID / 4)) {
    src = X; dst = Xb; idx = i;
  } else {
    int j = i - (MTOT * HID / 4);
    int sel = j >> 18;
    idx = j & 262143;
    src = (sel == 0) ? Wq : (sel == 1) ? Wk : Wv;
    dst = Wb + (size_t)sel * 262144;
  }
  float4 v = src[idx];
  ushort4 o;
  o.x = f2bf(v.x); o.y = f2bf(v.y); o.z = f2bf(v.z); o.w = f2bf(v.w);
  dst[idx] = o;
}

// ---------------- fused QKV projection GEMM ----------------
// BK=32 TRIPLE-buffered, 1 barrier/step, STAGE after barrier, counted vmcnt.
// Q pre-scaled by 0.125*log2(e) so attention softmax runs in exp2 domain.
__global__ __launch_bounds__(256) void qkv_gemm(
    const ushort* __restrict__ Xb,    // [4096][1024] bf16
    const ushort* __restrict__ Wb,    // [3072][1024] bf16 (Wq|Wk|Wv)
    const float* __restrict__ bq,
    const float* __restrict__ bk,
    const float* __restrict__ bv,
    ushort* __restrict__ Q,           // [B*H][S][64]
    ushort* __restrict__ K,           // [B*H][S][64]
    ushort* __restrict__ Vt)          // [B*H][64][S]
{
  __shared__ __attribute__((aligned(16))) ushort Al[3][128 * 32]; // 3x8KB
  __shared__ __attribute__((aligned(16))) ushort Bl[3][128 * 32]; // 3x8KB

  int bid = blockIdx.x;               // 768 blocks
  int swz = (bid & 7) * 96 + (bid >> 3);  // XCD swizzle (768 % 8 == 0)
  const int nbn = 3072 / 128;         // 24
  int bm = swz / nbn, bn = swz % nbn;
  int m0 = bm * 128, n0 = bn * 128;

  int tid = threadIdx.x;
  int wave = tid >> 6, lane = tid & 63;
  int g = lane >> 4, c = lane & 15;
  int wr = wave >> 1, wc = wave & 1;  // 2x2 waves, each 64x64 output

  // staging: per K-step each thread issues 2 A-loads + 2 B-loads (16B).
  // LDS dest linear; bank swizzle via XOR on the GLOBAL 16B-chunk index.
  int srow = tid >> 2;                // 0..63
  int schunk = tid & 3;
  int ssw = (srow >> 1) & 3;
  const ushort* Asrc0 = Xb + (size_t)(m0 + srow) * 1024 + ((schunk ^ ssw) << 3);
  const ushort* Asrc1 = Xb + (size_t)(m0 + 64 + srow) * 1024 + ((schunk ^ ssw) << 3);
  const ushort* Bsrc0 = Wb + (size_t)(n0 + srow) * 1024 + ((schunk ^ ssw) << 3);
  const ushort* Bsrc1 = Wb + (size_t)(n0 + 64 + srow) * 1024 + ((schunk ^ ssw) << 3);
  int soff = srow * 64 + schunk * 16;

#define GSTAGE(bi) do {                                   \
    char* la_ = (char*)Al[bi]; char* lb_ = (char*)Bl[bi]; \
    async16(la_ + soff,        Asrc0);                    \
    async16(la_ + 4096 + soff, Asrc1);                    \
    async16(lb_ + soff,        Bsrc0);                    \
    async16(lb_ + 4096 + soff, Bsrc1);                    \
    Asrc0 += 32; Asrc1 += 32; Bsrc0 += 32; Bsrc1 += 32;   \
  } while (0)

  f32x4 acc[4][4] = {};
  int rsw = (c >> 1) & 3;             // read-side swizzle
  int ch = ((g ^ rsw) << 4);          // swizzled 16B chunk byte offset

  GSTAGE(0);                          // prologue: 2 steps in flight
  GSTAGE(1);

  int cur = 0, nxt = 2;
  for (int ks = 0; ks < 32; ++ks) {
    if (ks < 31) {
      asm volatile("s_waitcnt vmcnt(4)" ::: "memory");  // cur landed, next in flight
    } else {
      asm volatile("s_waitcnt vmcnt(0)" ::: "memory");
    }
    __builtin_amdgcn_sched_barrier(0);
    __builtin_amdgcn_s_barrier();     // all waves: cur tile complete
    __builtin_amdgcn_sched_barrier(0);
    if (ks < 30) GSTAGE(nxt);         // safe: all waves past reads of buf[nxt]

    const char* la = (const char*)Al[cur];
    const char* lb = (const char*)Bl[cur];
    bf16x8 a[4], b[4];
    #pragma unroll
    for (int m = 0; m < 4; ++m)
      a[m] = *(const bf16x8*)(la + (wr * 64 + m * 16 + c) * 64 + ch);
    #pragma unroll
    for (int n = 0; n < 4; ++n)
      b[n] = *(const bf16x8*)(lb + (wc * 64 + n * 16 + c) * 64 + ch);
    __builtin_amdgcn_s_setprio(1);
    #pragma unroll
    for (int m = 0; m < 4; ++m)
      #pragma unroll
      for (int n = 0; n < 4; ++n)
        acc[m][n] = __builtin_amdgcn_mfma_f32_16x16x32_bf16(a[m], b[n], acc[m][n], 0, 0, 0);
    __builtin_amdgcn_s_setprio(0);

    cur = (cur == 2) ? 0 : cur + 1;
    nxt = (nxt == 2) ? 0 : nxt + 1;
  }
#undef GSTAGE

  int sel = n0 >> 10;
  const float* bp = (sel == 0) ? bq : (sel == 1) ? bk : bv;
  float scl = (sel == 0) ? 0.125f * LOG2E : 1.0f;

  #pragma unroll
  for (int n = 0; n < 4; ++n) {
    int nn = (n0 & 1023) + wc * 64 + n * 16 + c;
    float bias = bp[nn];
    int h = nn >> 6, d = nn & 63;
    #pragma unroll
    for (int m = 0; m < 4; ++m) {
      int rowg = m0 + wr * 64 + m * 16 + g * 4;
      int bb = rowg >> 10;
      int s = rowg & 1023;
      #pragma unroll
      for (int r = 0; r < 4; ++r) {
        float val = (acc[m][n][r] + bias) * scl;
        unsigned short ob = f2bf(val);
        if (sel == 0)
          Q[(size_t)((bb * 16 + h) * 1024 + s + r) * 64 + d] = ob;
        else if (sel == 1)
          K[(size_t)((bb * 16 + h) * 1024 + s + r) * 64 + d] = ob;
        else
          Vt[(size_t)((bb * 16 + h) * 64 + d) * 1024 + s + r] = ob;
      }
    }
  }
}

// Build two PV A-fragments from 16 P values (C-layout) — 8 cvt_pk + 4
// permlane32_swap, no LDS.
__device__ __forceinline__ void build_pa(const f32x16& p, bf16x8& pa0, bf16x8& pa1) {
  unsigned W0 = cvtpk(p[0],  p[1]);
  unsigned W1 = cvtpk(p[2],  p[3]);
  unsigned W2 = cvtpk(p[4],  p[5]);
  unsigned W3 = cvtpk(p[6],  p[7]);
  unsigned W4 = cvtpk(p[8],  p[9]);
  unsigned W5 = cvtpk(p[10], p[11]);
  unsigned W6 = cvtpk(p[12], p[13]);
  unsigned W7 = cvtpk(p[14], p[15]);
  pl32swap(W0, W2);
  pl32swap(W1, W3);
  pl32swap(W4, W6);
  pl32swap(W5, W7);
  union { unsigned u[4]; bf16x8 v; } a0, a1;
  a0.u[0] = W0; a0.u[1] = W1; a0.u[2] = W2; a0.u[3] = W3;
  a1.u[0] = W4; a1.u[1] = W5; a1.u[2] = W6; a1.u[3] = W7;
  pa0 = a0.v; pa1 = a1.v;
}

// ---------------- flash attention, 32x32 swapped orientation ----------------
// Triple-buffered K/V staging, 1 barrier/iter, mask in LDS (vmcnt stays clean).
__global__ __launch_bounds__(256) void attn(
    const ushort* __restrict__ Q,    // [B*H][S][64], pre-scaled 0.125*log2e
    const ushort* __restrict__ K,    // [B*H][S][64]
    const ushort* __restrict__ Vt,   // [B*H][64][S]
    const float* __restrict__ mask,  // [B][S]
    float* __restrict__ out)         // [B][S][1024]
{
  __shared__ __attribute__((aligned(16))) char kv_lds[3][16384]; // [K 8K][V 8K] x3
  __shared__ float mask_s[SS];                                   // 4 KB (log2-domain)

  int blk = blockIdx.x;           // 512
  int xcd = blk & 7;
  int j = blk >> 3;               // 0..63
  int bh = xcd * 8 + (j >> 3);    // 8 heads per XCD
  int qt = j & 7;
  int b = bh >> 4, h = bh & 15;
  int tid = threadIdx.x, wave = tid >> 6, lane = tid & 63;
  int r31 = lane & 31, hi = lane >> 5;
  int rsw = r31 & 7;
  int hib = hi << 4;
  int q0 = qt * 128 + wave * 32;

  const ushort* Qb = Q + (size_t)bh * SS * 64;
  const ushort* Kb = K + (size_t)bh * SS * 64;
  const ushort* Vb = Vt + (size_t)bh * 64 * SS;

  // mask to LDS, pre-multiplied by log2e (off the vmcnt path in the loop)
  for (int i = tid; i < SS; i += 256) mask_s[i] = mask[b * SS + i] * LOG2E;

  bf16x8 qf[4];
  #pragma unroll
  for (int kp = 0; kp < 4; ++kp)
    qf[kp] = *(const bf16x8*)(Qb + (size_t)(q0 + r31) * 64 + kp * 16 + hi * 8);

  int srow = lane >> 3;
  int schunk = lane & 7;
  const ushort* sptr[4];
  int soff[4];
  #pragma unroll
  for (int j2 = 0; j2 < 4; ++j2) {
    soff[j2] = wave * 4096 + j2 * 1024;
    if (wave < 2) {
      int row = wave * 32 + j2 * 8 + srow;
      sptr[j2] = Kb + (size_t)row * 64 + ((schunk ^ srow) << 3);
    } else {
      int d = (wave - 2) * 32 + j2 * 8 + srow;
      sptr[j2] = Vb + (size_t)d * SS + ((schunk ^ srow) << 3);
    }
  }
  const int sstep = (wave < 2) ? 64 * 64 : 64;

#define STAGE(bufidx) do {                              \
    char* lb_ = kv_lds[bufidx];                         \
    async16(lb_ + soff[0], sptr[0]);                    \
    async16(lb_ + soff[1], sptr[1]);                    \
    async16(lb_ + soff[2], sptr[2]);                    \
    async16(lb_ + soff[3], sptr[3]);                    \
    sptr[0] += sstep; sptr[1] += sstep;                 \
    sptr[2] += sstep; sptr[3] += sstep;                 \
  } while (0)

  __syncthreads();                // mask_s visible to all waves
  STAGE(0);                       // prologue: 2 tiles in flight
  STAGE(1);

  f32x16 o0 = (f32x16)0.0f, o1 = (f32x16)0.0f;
  float mrow = 0.f, lrow = 0.f;

  int cur = 0, nxt = 2;
  for (int it = 0; it < 16; ++it) {
    if (it < 15) {
      asm volatile("s_waitcnt vmcnt(4)" ::: "memory");
    } else {
      asm volatile("s_waitcnt vmcnt(0)" ::: "memory");
    }
    __builtin_amdgcn_sched_barrier(0);
    __builtin_amdgcn_s_barrier();
    __builtin_amdgcn_sched_barrier(0);
    if (it < 14) STAGE(nxt);

    const char* kb0 = kv_lds[cur];
    const char* vb0 = kv_lds[cur] + 8192;

    f32x16 s0 = (f32x16)0.0f, s1 = (f32x16)0.0f;
    __builtin_amdgcn_s_setprio(1);
    #pragma unroll
    for (int kp = 0; kp < 4; ++kp) {
      int ch = (((kp << 1) | hi) ^ rsw) << 4;
      bf16x8 ka = *(const bf16x8*)(kb0 + r31 * 128 + ch);
      bf16x8 kc = *(const bf16x8*)(kb0 + (32 + r31) * 128 + ch);
      s0 = __builtin_amdgcn_mfma_f32_32x32x16_bf16(ka, qf[kp], s0, 0, 0, 0);
      s1 = __builtin_amdgcn_mfma_f32_32x32x16_bf16(kc, qf[kp], s1, 0, 0, 0);
    }
    __builtin_amdgcn_s_setprio(0);

    int kv = it * 64;
    #pragma unroll
    for (int sq = 0; sq < 4; ++sq) {
      f32x4 mk0 = *(const f32x4*)(&mask_s[kv + sq * 8 + hi * 4]);
      f32x4 mk1 = *(const f32x4*)(&mask_s[kv + 32 + sq * 8 + hi * 4]);
      #pragma unroll
      for (int r = 0; r < 4; ++r) {
        s0[sq * 4 + r] += mk0[r];
        s1[sq * 4 + r] += mk1[r];
      }
    }

    float mx = s0[0];
    #pragma unroll
    for (int i = 1; i < 16; ++i) mx = fmaxf(mx, s0[i]);
    #pragma unroll
    for (int i = 0; i < 16; ++i) mx = fmaxf(mx, s1[i]);
    mx = fmaxf(mx, __shfl_xor(mx, 32));

    if (!__all(mx <= mrow + 11.5416f)) {
      float mn = fmaxf(mrow, mx);
      float sc = exp2fast(mrow - mn);
      mrow = mn;
      lrow *= sc;
      #pragma unroll
      for (int i = 0; i < 16; ++i) {
        int qh = (i & 3) + 8 * (i >> 2);
        float scq = __uint_as_float((unsigned)__builtin_amdgcn_ds_bpermute(
            (qh << 2) + hib, (int)__float_as_uint(sc)));
        o0[i] *= scq; o1[i] *= scq;
      }
    }

    f32x16 p0, p1;
    float rs = 0.f;
    #pragma unroll
    for (int i = 0; i < 16; ++i) { float e = exp2fast(s0[i] - mrow); p0[i] = e; rs += e; }
    #pragma unroll
    for (int i = 0; i < 16; ++i) { float e = exp2fast(s1[i] - mrow); p1[i] = e; rs += e; }
    rs += __shfl_xor(rs, 32);
    lrow += rs;

    #pragma unroll
    for (int T = 0; T < 2; ++T) {
      bf16x8 pa0, pa1;
      build_pa(T ? p1 : p0, pa0, pa1);
      __builtin_amdgcn_s_setprio(1);
      #pragma unroll
      for (int kh = 0; kh < 2; ++kh) {
        int kap = 2 * T + kh;
        int ch = (((kap << 1) | hi) ^ rsw) << 4;
        bf16x8 va = *(const bf16x8*)(vb0 + r31 * 128 + ch);
        bf16x8 vc = *(const bf16x8*)(vb0 + (32 + r31) * 128 + ch);
        bf16x8 pf = kh ? pa1 : pa0;
        o0 = __builtin_amdgcn_mfma_f32_32x32x16_bf16(pf, va, o0, 0, 0, 0);
        o1 = __builtin_amdgcn_mfma_f32_32x32x16_bf16(pf, vc, o1, 0, 0, 0);
      }
      __builtin_amdgcn_s_setprio(0);
    }

    cur = (cur == 2) ? 0 : cur + 1;
    nxt = (nxt == 2) ? 0 : nxt + 1;
  }
#undef STAGE

  float inv = 1.0f / lrow;
  #pragma unroll
  for (int i = 0; i < 16; ++i) {
    int qh = (i & 3) + 8 * (i >> 2);
    float li = __uint_as_float((unsigned)__builtin_amdgcn_ds_bpermute(
        (qh << 2) + hib, (int)__float_as_uint(inv)));
    int row = q0 + qh + 4 * hi;
    float* op = out + (size_t)(b * SS + row) * 1024 + h * 64 + r31;
    op[0]  = o0[i] * li;
    op[32] = o1[i] * li;
  }
}

extern "C" void kernel_launch(void* const* d_in, const int* in_sizes, int n_in,
                              void* d_out, int out_size, void* d_ws, size_t ws_size,
                              hipStream_t stream) {
  const float* hs   = (const float*)d_in[0];
  const float* mask = (const float*)d_in[1];
  const float* Wq   = (const float*)d_in[2];
  const float* bq   = (const float*)d_in[3];
  const float* Wk   = (const float*)d_in[4];
  const float* bk   = (const float*)d_in[5];
  const float* Wv   = (const float*)d_in[6];
  const float* bv   = (const float*)d_in[7];
  float* out = (float*)d_out;

  char* ws = (char*)d_ws;
  ushort* Xb = (ushort*)(ws);                    // 8 MB  [4096][1024]
  ushort* Wb = (ushort*)(ws + (8u  << 20));      // 6 MB  [3072][1024]
  ushort* Qp = (ushort*)(ws + (14u << 20));      // 8 MB  [64][1024][64]
  ushort* Kp = (ushort*)(ws + (22u << 20));      // 8 MB  [64][1024][64]
  ushort* Vt = (ushort*)(ws + (30u << 20));      // 8 MB  [64][64][1024]

  cvt_all<<<7168, 256, 0, stream>>>((const float4*)hs, (const float4*)Wq,
                                    (const float4*)Wk, (const float4*)Wv,
                                    (ushort4*)Xb, (ushort4*)Wb);
  qkv_gemm<<<768, 256, 0, stream>>>(Xb, Wb, bq, bk, bv, Qp, Kp, Vt);
  attn<<<512, 256, 0, stream>>>(Qp, Kp, Vt, mask, out);
}